// Round 1
// baseline (1319.281 us; speedup 1.0000x reference)
//
#include <hip/hip_runtime.h>
#include <hip/hip_bf16.h>

typedef float f32x4 __attribute__((ext_vector_type(4)));
typedef short s16x8 __attribute__((ext_vector_type(8)));
typedef unsigned int u32x4 __attribute__((ext_vector_type(4)));

#define DEV static __device__ __forceinline__

DEV unsigned short f2bf(float x){
    unsigned u = __builtin_bit_cast(unsigned, x);
    u += 0x7FFFu + ((u >> 16) & 1u);
    return (unsigned short)(u >> 16);
}
DEV float bf2f(unsigned short h){
    unsigned u = ((unsigned)h) << 16;
    return __builtin_bit_cast(float, u);
}
DEV float sigm_(float x){ return 1.0f / (1.0f + __expf(-x)); }
DEV float silu_(float x){ return x / (1.0f + __expf(-x)); }

// ---------------- weight transpose + convert:  src [B][K][64] f32 -> dst [B][64][K] bf16
__global__ __launch_bounds__(256) void k_transconv(const float* __restrict__ src,
                                                   unsigned short* __restrict__ dst,
                                                   int K, int total){
    int gid = blockIdx.x * 256 + threadIdx.x;
    if (gid >= total) return;
    int kn  = K * 64;
    int b   = gid / kn;
    int rem = gid - b * kn;
    int k   = rem >> 6, n = rem & 63;
    dst[b * kn + n * K + k] = f2bf(src[gid]);
}

// ---------------- atom embedding gather
__global__ __launch_bounds__(256) void k_embed(const float* __restrict__ emb,
                                               const int* __restrict__ z,
                                               unsigned short* __restrict__ out){
    int gid = blockIdx.x * 256 + threadIdx.x;   // N_ATOMS*64
    int n = gid >> 6, f = gid & 63;
    out[gid] = f2bf(emb[z[n] * 64 + f]);
}

// ---------------- bases[rows][9] @ W[9][64] -> bf16 out[rows][64]
__global__ __launch_bounds__(256) void k_smallmm(const float* __restrict__ bases,
                                                 const float* __restrict__ W,
                                                 unsigned short* __restrict__ out){
    int gid = blockIdx.x * 256 + threadIdx.x;
    int r = gid >> 6, f = gid & 63;
    const float* b = bases + r * 9;
    float acc = 0.f;
    #pragma unroll
    for (int k = 0; k < 9; ++k) acc += b[k] * W[k * 64 + f];
    out[gid] = f2bf(acc);
}

// ---------------- atom conv: gathered gmlp over edges, scatter to s_atom
__global__ __launch_bounds__(256) void k_atom_conv(
    const unsigned short* __restrict__ atomBf, const unsigned short* __restrict__ bondBf,
    const unsigned short* __restrict__ bwagBf,
    const int* __restrict__ agraph, const int* __restrict__ d2u,
    const unsigned short* __restrict__ w1cT, const unsigned short* __restrict__ w1gT,
    const unsigned short* __restrict__ w2cT, const unsigned short* __restrict__ w2gT,
    const float* __restrict__ cb1, const float* __restrict__ cb2,
    const float* __restrict__ gb1, const float* __restrict__ gb2,
    float* __restrict__ s_atom)
{
    __shared__ unsigned short ldsA[64 * 200];   // msg tile [64 rows][192] pad->200
    __shared__ unsigned short ldsHC[64 * 72];   // hidden core, pad 64->72
    __shared__ unsigned short ldsHG[64 * 72];   // hidden gate
    const int tid = threadIdx.x;
    const int r0  = blockIdx.x * 64;

    // stage: 64 rows x 24 chunks of 8 bf16
    for (int c = tid; c < 64 * 24; c += 256){
        int row = c / 24, seg = c - row * 24;
        int e = r0 + row;
        int f8 = (seg & 7) * 8;
        const unsigned short* src;
        if (seg < 8)       src = atomBf + agraph[2 * e]     * 64 + f8;
        else if (seg < 16) src = bondBf + d2u[e]            * 64 + f8;
        else               src = atomBf + agraph[2 * e + 1] * 64 + f8;
        *(u32x4*)&ldsA[row * 200 + seg * 8] = *(const u32x4*)src;
    }
    __syncthreads();

    const int lane = tid & 63;
    const int r16  = lane & 15;
    const int grp  = lane >> 4;
    const int col  = (tid >> 6) * 16 + r16;   // this wave's output column

    // preload B fragments (weights transposed: [64][K])
    s16x8 bc1[6], bg1[6], bc2[2], bg2[2];
    #pragma unroll
    for (int kt = 0; kt < 6; ++kt){
        bc1[kt] = *(const s16x8*)&w1cT[col * 192 + kt * 32 + grp * 8];
        bg1[kt] = *(const s16x8*)&w1gT[col * 192 + kt * 32 + grp * 8];
    }
    #pragma unroll
    for (int kt = 0; kt < 2; ++kt){
        bc2[kt] = *(const s16x8*)&w2cT[col * 64 + kt * 32 + grp * 8];
        bg2[kt] = *(const s16x8*)&w2gT[col * 64 + kt * 32 + grp * 8];
    }

    f32x4 aC[4] = {}, aG[4] = {};
    #pragma unroll
    for (int kt = 0; kt < 6; ++kt){
        #pragma unroll
        for (int mt = 0; mt < 4; ++mt){
            s16x8 a = *(const s16x8*)&ldsA[(mt * 16 + r16) * 200 + kt * 32 + grp * 8];
            aC[mt] = __builtin_amdgcn_mfma_f32_16x16x32_bf16(a, bc1[kt], aC[mt], 0, 0, 0);
            aG[mt] = __builtin_amdgcn_mfma_f32_16x16x32_bf16(a, bg1[kt], aG[mt], 0, 0, 0);
        }
    }
    const float bC1 = cb1[col], bG1 = gb1[col];
    #pragma unroll
    for (int mt = 0; mt < 4; ++mt){
        #pragma unroll
        for (int j = 0; j < 4; ++j){
            int row = mt * 16 + grp * 4 + j;     // D layout: row=(lane>>4)*4+reg
            ldsHC[row * 72 + col] = f2bf(silu_(aC[mt][j] + bC1));
            ldsHG[row * 72 + col] = f2bf(silu_(aG[mt][j] + bG1));
        }
    }
    __syncthreads();

    f32x4 oC[4] = {}, oG[4] = {};
    #pragma unroll
    for (int kt = 0; kt < 2; ++kt){
        #pragma unroll
        for (int mt = 0; mt < 4; ++mt){
            s16x8 hc = *(const s16x8*)&ldsHC[(mt * 16 + r16) * 72 + kt * 32 + grp * 8];
            s16x8 hg = *(const s16x8*)&ldsHG[(mt * 16 + r16) * 72 + kt * 32 + grp * 8];
            oC[mt] = __builtin_amdgcn_mfma_f32_16x16x32_bf16(hc, bc2[kt], oC[mt], 0, 0, 0);
            oG[mt] = __builtin_amdgcn_mfma_f32_16x16x32_bf16(hg, bg2[kt], oG[mt], 0, 0, 0);
        }
    }
    const float bC2 = cb2[col], bG2 = gb2[col];
    #pragma unroll
    for (int mt = 0; mt < 4; ++mt){
        #pragma unroll
        for (int j = 0; j < 4; ++j){
            int e = r0 + mt * 16 + grp * 4 + j;
            float v = silu_(oC[mt][j] + bC2) * sigm_(oG[mt][j] + bG2);
            v *= bf2f(bwagBf[d2u[e] * 64 + col]);
            atomicAdd(&s_atom[agraph[2 * e] * 64 + col], v);
        }
    }
}

// ---------------- bond conv: gathered gmlp over angles, scatter to s_bond
__global__ __launch_bounds__(256) void k_bond_conv(
    const unsigned short* __restrict__ atomBf, const unsigned short* __restrict__ bondBf,
    const unsigned short* __restrict__ angleBf, const unsigned short* __restrict__ bwbgBf,
    const int* __restrict__ bga, const int* __restrict__ bgb,
    const unsigned short* __restrict__ w1cT, const unsigned short* __restrict__ w1gT,
    const unsigned short* __restrict__ w2cT, const unsigned short* __restrict__ w2gT,
    const float* __restrict__ cb1, const float* __restrict__ cb2,
    const float* __restrict__ gb1, const float* __restrict__ gb2,
    float* __restrict__ s_bond)
{
    __shared__ unsigned short ldsA[64 * 264];   // tot tile [64][256] pad->264
    __shared__ unsigned short ldsHC[64 * 72];
    __shared__ unsigned short ldsHG[64 * 72];
    const int tid = threadIdx.x;
    const int r0  = blockIdx.x * 64;

    for (int c = tid; c < 64 * 32; c += 256){
        int row = c >> 5, seg = c & 31;
        int a = r0 + row;
        int f8 = (seg & 7) * 8;
        const unsigned short* src;
        if (seg < 8)       src = bondBf  + bgb[2 * a]     * 64 + f8;
        else if (seg < 16) src = bondBf  + bgb[2 * a + 1] * 64 + f8;
        else if (seg < 24) src = angleBf + (size_t)a      * 64 + f8;
        else               src = atomBf  + bga[a]         * 64 + f8;
        *(u32x4*)&ldsA[row * 264 + seg * 8] = *(const u32x4*)src;
    }
    __syncthreads();

    const int lane = tid & 63;
    const int r16  = lane & 15;
    const int grp  = lane >> 4;
    const int col  = (tid >> 6) * 16 + r16;

    s16x8 bc1[8], bg1[8], bc2[2], bg2[2];
    #pragma unroll
    for (int kt = 0; kt < 8; ++kt){
        bc1[kt] = *(const s16x8*)&w1cT[col * 256 + kt * 32 + grp * 8];
        bg1[kt] = *(const s16x8*)&w1gT[col * 256 + kt * 32 + grp * 8];
    }
    #pragma unroll
    for (int kt = 0; kt < 2; ++kt){
        bc2[kt] = *(const s16x8*)&w2cT[col * 64 + kt * 32 + grp * 8];
        bg2[kt] = *(const s16x8*)&w2gT[col * 64 + kt * 32 + grp * 8];
    }

    f32x4 aC[4] = {}, aG[4] = {};
    #pragma unroll
    for (int kt = 0; kt < 8; ++kt){
        #pragma unroll
        for (int mt = 0; mt < 4; ++mt){
            s16x8 a = *(const s16x8*)&ldsA[(mt * 16 + r16) * 264 + kt * 32 + grp * 8];
            aC[mt] = __builtin_amdgcn_mfma_f32_16x16x32_bf16(a, bc1[kt], aC[mt], 0, 0, 0);
            aG[mt] = __builtin_amdgcn_mfma_f32_16x16x32_bf16(a, bg1[kt], aG[mt], 0, 0, 0);
        }
    }
    const float bC1 = cb1[col], bG1 = gb1[col];
    #pragma unroll
    for (int mt = 0; mt < 4; ++mt){
        #pragma unroll
        for (int j = 0; j < 4; ++j){
            int row = mt * 16 + grp * 4 + j;
            ldsHC[row * 72 + col] = f2bf(silu_(aC[mt][j] + bC1));
            ldsHG[row * 72 + col] = f2bf(silu_(aG[mt][j] + bG1));
        }
    }
    __syncthreads();

    f32x4 oC[4] = {}, oG[4] = {};
    #pragma unroll
    for (int kt = 0; kt < 2; ++kt){
        #pragma unroll
        for (int mt = 0; mt < 4; ++mt){
            s16x8 hc = *(const s16x8*)&ldsHC[(mt * 16 + r16) * 72 + kt * 32 + grp * 8];
            s16x8 hg = *(const s16x8*)&ldsHG[(mt * 16 + r16) * 72 + kt * 32 + grp * 8];
            oC[mt] = __builtin_amdgcn_mfma_f32_16x16x32_bf16(hc, bc2[kt], oC[mt], 0, 0, 0);
            oG[mt] = __builtin_amdgcn_mfma_f32_16x16x32_bf16(hg, bg2[kt], oG[mt], 0, 0, 0);
        }
    }
    const float bC2 = cb2[col], bG2 = gb2[col];
    #pragma unroll
    for (int mt = 0; mt < 4; ++mt){
        #pragma unroll
        for (int j = 0; j < 4; ++j){
            int a = r0 + mt * 16 + grp * 4 + j;
            float v = silu_(oC[mt][j] + bC2) * sigm_(oG[mt][j] + bG2);
            v *= bf2f(bwbgBf[bgb[2 * a] * 64 + col]);
            atomicAdd(&s_bond[bgb[2 * a] * 64 + col], v);
        }
    }
}

// ---------------- angle update (single gated layer), in-place residual on angleBf
__global__ __launch_bounds__(256) void k_angle(
    const unsigned short* __restrict__ atomBf, const unsigned short* __restrict__ bondBf,
    unsigned short* __restrict__ angleBf,
    const int* __restrict__ bga, const int* __restrict__ bgb,
    const unsigned short* __restrict__ wcT, const unsigned short* __restrict__ wgT,
    const float* __restrict__ cb, const float* __restrict__ gb)
{
    __shared__ unsigned short ldsA[64 * 264];
    const int tid = threadIdx.x;
    const int r0  = blockIdx.x * 64;

    for (int c = tid; c < 64 * 32; c += 256){
        int row = c >> 5, seg = c & 31;
        int a = r0 + row;
        int f8 = (seg & 7) * 8;
        const unsigned short* src;
        if (seg < 8)       src = bondBf  + bgb[2 * a]     * 64 + f8;
        else if (seg < 16) src = bondBf  + bgb[2 * a + 1] * 64 + f8;
        else if (seg < 24) src = angleBf + (size_t)a      * 64 + f8;
        else               src = atomBf  + bga[a]         * 64 + f8;
        *(u32x4*)&ldsA[row * 264 + seg * 8] = *(const u32x4*)src;
    }
    __syncthreads();

    const int lane = tid & 63;
    const int r16  = lane & 15;
    const int grp  = lane >> 4;
    const int col  = (tid >> 6) * 16 + r16;

    s16x8 bc[8], bg_[8];
    #pragma unroll
    for (int kt = 0; kt < 8; ++kt){
        bc[kt]  = *(const s16x8*)&wcT[col * 256 + kt * 32 + grp * 8];
        bg_[kt] = *(const s16x8*)&wgT[col * 256 + kt * 32 + grp * 8];
    }
    f32x4 aC[4] = {}, aG[4] = {};
    #pragma unroll
    for (int kt = 0; kt < 8; ++kt){
        #pragma unroll
        for (int mt = 0; mt < 4; ++mt){
            s16x8 a = *(const s16x8*)&ldsA[(mt * 16 + r16) * 264 + kt * 32 + grp * 8];
            aC[mt] = __builtin_amdgcn_mfma_f32_16x16x32_bf16(a, bc[kt],  aC[mt], 0, 0, 0);
            aG[mt] = __builtin_amdgcn_mfma_f32_16x16x32_bf16(a, bg_[kt], aG[mt], 0, 0, 0);
        }
    }
    const float bC = cb[col], bG = gb[col];
    #pragma unroll
    for (int mt = 0; mt < 4; ++mt){
        #pragma unroll
        for (int j = 0; j < 4; ++j){
            int row = mt * 16 + grp * 4 + j;
            int a = r0 + row;
            float oldv = bf2f(ldsA[row * 264 + 128 + col]);   // angle segment of tot
            float v = silu_(aC[mt][j] + bC) * sigm_(aG[mt][j] + bG);
            angleBf[(size_t)a * 64 + col] = f2bf(oldv + v);
        }
    }
}

// ---------------- residual:  act[row] += s[row] @ W   (W fp32 [64][64], act bf16)
__global__ __launch_bounds__(256) void k_resmm(const float* __restrict__ s,
                                               const float* __restrict__ W,
                                               unsigned short* __restrict__ act){
    int gid = blockIdx.x * 256 + threadIdx.x;
    int row = gid >> 6, f = gid & 63;
    const float* srow = s + (size_t)row * 64;
    float acc = 0.f;
    #pragma unroll
    for (int k = 0; k < 64; ++k) acc += srow[k] * W[k * 64 + f];
    act[gid] = f2bf(bf2f(act[gid]) + acc);
}

// ---------------- readout MLP + segmented sum (wave per atom row)
__global__ __launch_bounds__(256) void k_readout(
    const unsigned short* __restrict__ atomBf, const int* __restrict__ owners,
    const float* __restrict__ w1, const float* __restrict__ b1,
    const float* __restrict__ w2, const float* __restrict__ b2,
    const float* __restrict__ w3, const float* __restrict__ b3,
    float* __restrict__ esum, float* __restrict__ cnt)
{
    int gid  = blockIdx.x * 256 + threadIdx.x;
    int n    = gid >> 6;
    int lane = threadIdx.x & 63;
    float a = bf2f(atomBf[n * 64 + lane]);
    float acc = b1[lane];
    #pragma unroll
    for (int k = 0; k < 64; ++k) acc += __shfl(a, k) * w1[k * 64 + lane];
    float h = silu_(acc);
    acc = b2[lane];
    #pragma unroll
    for (int k = 0; k < 64; ++k) acc += __shfl(h, k) * w2[k * 64 + lane];
    h = silu_(acc);
    float p = h * w3[lane];
    #pragma unroll
    for (int off = 32; off > 0; off >>= 1) p += __shfl_xor(p, off);
    if (lane == 0){
        atomicAdd(&esum[owners[n]], p + b3[0]);
        atomicAdd(&cnt[owners[n]], 1.0f);
    }
}

__global__ void k_final(const float* __restrict__ esum, const float* __restrict__ cnt,
                        float* __restrict__ out){
    int i = threadIdx.x;
    if (i < 128) out[i] = esum[i] / fmaxf(cnt[i], 1.0f);
}

extern "C" void kernel_launch(void* const* d_in, const int* in_sizes, int n_in,
                              void* d_out, int out_size, void* d_ws, size_t ws_size,
                              hipStream_t stream)
{
    (void)in_sizes; (void)n_in; (void)out_size; (void)ws_size;
    const int   N_ATOMS = 8192, N_UND = 65536, N_DIR = 131072, N_ANG = 262144;

    const int*   atomic_numbers = (const int*)  d_in[0];
    const float* bb_ag  = (const float*)d_in[1];
    const float* bb_bg  = (const float*)d_in[2];
    const float* ang_b  = (const float*)d_in[3];
    const int*   agraph = (const int*)  d_in[4];
    const int*   d2u    = (const int*)  d_in[5];
    const int*   bga    = (const int*)  d_in[6];
    const int*   bgb    = (const int*)  d_in[7];
    const int*   owners = (const int*)  d_in[8];
    const float* emb    = (const float*)d_in[9];
    const float* Wb     = (const float*)d_in[10];
    const float* Wa     = (const float*)d_in[11];
    const float* Wbwag  = (const float*)d_in[12];
    const float* Wbwbg  = (const float*)d_in[13];
    const float* ac_cw1 = (const float*)d_in[14];
    const float* ac_cb1 = (const float*)d_in[15];
    const float* ac_cw2 = (const float*)d_in[16];
    const float* ac_cb2 = (const float*)d_in[17];
    const float* ac_gw1 = (const float*)d_in[18];
    const float* ac_gb1 = (const float*)d_in[19];
    const float* ac_gw2 = (const float*)d_in[20];
    const float* ac_gb2 = (const float*)d_in[21];
    const float* ac_out = (const float*)d_in[22];
    const float* bc_cw1 = (const float*)d_in[23];
    const float* bc_cb1 = (const float*)d_in[24];
    const float* bc_cw2 = (const float*)d_in[25];
    const float* bc_cb2 = (const float*)d_in[26];
    const float* bc_gw1 = (const float*)d_in[27];
    const float* bc_gb1 = (const float*)d_in[28];
    const float* bc_gw2 = (const float*)d_in[29];
    const float* bc_gb2 = (const float*)d_in[30];
    const float* bc_out = (const float*)d_in[31];
    const float* an_cw  = (const float*)d_in[32];
    const float* an_cb  = (const float*)d_in[33];
    const float* an_gw  = (const float*)d_in[34];
    const float* an_gb  = (const float*)d_in[35];
    const float* ro_w1  = (const float*)d_in[36];
    const float* ro_b1  = (const float*)d_in[37];
    const float* ro_w2  = (const float*)d_in[38];
    const float* ro_b2  = (const float*)d_in[39];
    const float* ro_w3  = (const float*)d_in[40];
    const float* ro_b3  = (const float*)d_in[41];

    char* ws = (char*)d_ws;
    size_t off = 0;
    auto alloc = [&](size_t bytes) -> void* {
        void* p = ws + off;
        off = (off + bytes + 255) & ~(size_t)255;
        return p;
    };
    unsigned short* atomBf  = (unsigned short*)alloc((size_t)N_ATOMS * 64 * 2);
    unsigned short* bondBf  = (unsigned short*)alloc((size_t)N_UND   * 64 * 2);
    unsigned short* angleBf = (unsigned short*)alloc((size_t)N_ANG   * 64 * 2);
    unsigned short* bwagBf  = (unsigned short*)alloc((size_t)N_UND   * 64 * 2);
    unsigned short* bwbgBf  = (unsigned short*)alloc((size_t)N_UND   * 64 * 2);
    float* s_atom = (float*)alloc((size_t)N_ATOMS * 64 * 4);
    float* s_bond = (float*)alloc((size_t)N_UND   * 64 * 4);
    float* esum   = (float*)alloc(128 * 4);
    float* cnt    = (float*)alloc(128 * 4);
    unsigned short* acw1cT = (unsigned short*)alloc((size_t)4 * 64 * 192 * 2);
    unsigned short* acw1gT = (unsigned short*)alloc((size_t)4 * 64 * 192 * 2);
    unsigned short* acw2cT = (unsigned short*)alloc((size_t)4 * 64 * 64 * 2);
    unsigned short* acw2gT = (unsigned short*)alloc((size_t)4 * 64 * 64 * 2);
    unsigned short* bcw1cT = (unsigned short*)alloc((size_t)3 * 64 * 256 * 2);
    unsigned short* bcw1gT = (unsigned short*)alloc((size_t)3 * 64 * 256 * 2);
    unsigned short* bcw2cT = (unsigned short*)alloc((size_t)3 * 64 * 64 * 2);
    unsigned short* bcw2gT = (unsigned short*)alloc((size_t)3 * 64 * 64 * 2);
    unsigned short* anwcT  = (unsigned short*)alloc((size_t)3 * 64 * 256 * 2);
    unsigned short* anwgT  = (unsigned short*)alloc((size_t)3 * 64 * 256 * 2);

    auto tc = [&](const float* src, unsigned short* dst, int B, int K){
        int total = B * K * 64;
        k_transconv<<<(total + 255) / 256, 256, 0, stream>>>(src, dst, K, total);
    };
    tc(ac_cw1, acw1cT, 4, 192);  tc(ac_gw1, acw1gT, 4, 192);
    tc(ac_cw2, acw2cT, 4, 64);   tc(ac_gw2, acw2gT, 4, 64);
    tc(bc_cw1, bcw1cT, 3, 256);  tc(bc_gw1, bcw1gT, 3, 256);
    tc(bc_cw2, bcw2cT, 3, 64);   tc(bc_gw2, bcw2gT, 3, 64);
    tc(an_cw,  anwcT,  3, 256);  tc(an_gw,  anwgT,  3, 256);

    k_embed<<<N_ATOMS * 64 / 256, 256, 0, stream>>>(emb, atomic_numbers, atomBf);
    k_smallmm<<<N_UND * 64 / 256, 256, 0, stream>>>(bb_ag, Wb,    bondBf);
    k_smallmm<<<N_ANG * 64 / 256, 256, 0, stream>>>(ang_b, Wa,    angleBf);
    k_smallmm<<<N_UND * 64 / 256, 256, 0, stream>>>(bb_ag, Wbwag, bwagBf);
    k_smallmm<<<N_UND * 64 / 256, 256, 0, stream>>>(bb_bg, Wbwbg, bwbgBf);

    for (int i = 0; i < 4; ++i){
        hipMemsetAsync(s_atom, 0, (size_t)N_ATOMS * 64 * 4, stream);
        k_atom_conv<<<N_DIR / 64, 256, 0, stream>>>(
            atomBf, bondBf, bwagBf, agraph, d2u,
            acw1cT + (size_t)i * 64 * 192, acw1gT + (size_t)i * 64 * 192,
            acw2cT + (size_t)i * 64 * 64,  acw2gT + (size_t)i * 64 * 64,
            ac_cb1 + i * 64, ac_cb2 + i * 64, ac_gb1 + i * 64, ac_gb2 + i * 64, s_atom);
        k_resmm<<<N_ATOMS * 64 / 256, 256, 0, stream>>>(s_atom, ac_out + (size_t)i * 64 * 64, atomBf);
        if (i == 3) break;
        hipMemsetAsync(s_bond, 0, (size_t)N_UND * 64 * 4, stream);
        k_bond_conv<<<N_ANG / 64, 256, 0, stream>>>(
            atomBf, bondBf, angleBf, bwbgBf, bga, bgb,
            bcw1cT + (size_t)i * 64 * 256, bcw1gT + (size_t)i * 64 * 256,
            bcw2cT + (size_t)i * 64 * 64,  bcw2gT + (size_t)i * 64 * 64,
            bc_cb1 + i * 64, bc_cb2 + i * 64, bc_gb1 + i * 64, bc_gb2 + i * 64, s_bond);
        k_resmm<<<N_UND * 64 / 256, 256, 0, stream>>>(s_bond, bc_out + (size_t)i * 64 * 64, bondBf);
        k_angle<<<N_ANG / 64, 256, 0, stream>>>(
            atomBf, bondBf, angleBf, bga, bgb,
            anwcT + (size_t)i * 64 * 256, anwgT + (size_t)i * 64 * 256,
            an_cb + i * 64, an_gb + i * 64);
    }

    hipMemsetAsync(esum, 0, 128 * 4, stream);
    hipMemsetAsync(cnt,  0, 128 * 4, stream);
    k_readout<<<N_ATOMS * 64 / 256, 256, 0, stream>>>(
        atomBf, owners, ro_w1, ro_b1, ro_w2, ro_b2, ro_w3, ro_b3, esum, cnt);
    k_final<<<1, 128, 0, stream>>>(esum, cnt, (float*)d_out);
}

// Round 2
// 1096.598 us; speedup vs baseline: 1.2031x; 1.2031x over previous
//
#include <hip/hip_runtime.h>
#include <hip/hip_bf16.h>

typedef float f32x4 __attribute__((ext_vector_type(4)));
typedef short s16x8 __attribute__((ext_vector_type(8)));
typedef unsigned int u32x4 __attribute__((ext_vector_type(4)));

#define DEV static __device__ __forceinline__

DEV unsigned short f2bf(float x){
    unsigned u = __builtin_bit_cast(unsigned, x);
    u += 0x7FFFu + ((u >> 16) & 1u);
    return (unsigned short)(u >> 16);
}
DEV float bf2f(unsigned short h){
    unsigned u = ((unsigned)h) << 16;
    return __builtin_bit_cast(float, u);
}
DEV float sigm_(float x){ return 1.0f / (1.0f + __expf(-x)); }
DEV float silu_(float x){ return x / (1.0f + __expf(-x)); }

// ---------------- weight transpose + convert:  src [B][K][64] f32 -> dst [B][64][K] bf16
__global__ __launch_bounds__(256) void k_transconv(const float* __restrict__ src,
                                                   unsigned short* __restrict__ dst,
                                                   int K, int total){
    int gid = blockIdx.x * 256 + threadIdx.x;
    if (gid >= total) return;
    int kn  = K * 64;
    int b   = gid / kn;
    int rem = gid - b * kn;
    int k   = rem >> 6, n = rem & 63;
    dst[b * kn + n * K + k] = f2bf(src[gid]);
}

// ---------------- atom embedding gather
__global__ __launch_bounds__(256) void k_embed(const float* __restrict__ emb,
                                               const int* __restrict__ z,
                                               unsigned short* __restrict__ out){
    int gid = blockIdx.x * 256 + threadIdx.x;
    int n = gid >> 6, f = gid & 63;
    out[gid] = f2bf(emb[z[n] * 64 + f]);
}

// ---------------- bases[rows][9] @ W[9][64] -> bf16 out[rows][64]
__global__ __launch_bounds__(256) void k_smallmm(const float* __restrict__ bases,
                                                 const float* __restrict__ W,
                                                 unsigned short* __restrict__ out){
    int gid = blockIdx.x * 256 + threadIdx.x;
    int r = gid >> 6, f = gid & 63;
    const float* b = bases + r * 9;
    float acc = 0.f;
    #pragma unroll
    for (int k = 0; k < 9; ++k) acc += b[k] * W[k * 64 + f];
    out[gid] = f2bf(acc);
}

// ---------------- CSR build helpers
__global__ void k_count(const int* __restrict__ dst, int stride, int n, int* __restrict__ cnt){
    int i = blockIdx.x * 256 + threadIdx.x;
    if (i < n) atomicAdd(&cnt[dst[(size_t)i * stride]], 1);
}

__global__ __launch_bounds__(1024) void k_scan(const int* __restrict__ cnt,
                                               int* __restrict__ offs, int n){
    __shared__ int part[1024];
    int t = threadIdx.x;
    int chunk = n >> 10;
    int base = t * chunk;
    int s = 0;
    for (int j = 0; j < chunk; ++j) s += cnt[base + j];
    part[t] = s;
    __syncthreads();
    for (int d = 1; d < 1024; d <<= 1){
        int v = (t >= d) ? part[t - d] : 0;
        __syncthreads();
        part[t] += v;
        __syncthreads();
    }
    int run = (t == 0) ? 0 : part[t - 1];
    for (int j = 0; j < chunk; ++j){
        offs[base + j] = run;
        run += cnt[base + j];
    }
    if (t == 1023) offs[n] = run;
}

__global__ void k_fill(const int* __restrict__ dst, int stride, int n,
                       const int* __restrict__ offs, int* __restrict__ cur,
                       int* __restrict__ idx){
    int i = blockIdx.x * 256 + threadIdx.x;
    if (i < n){
        int d = dst[(size_t)i * stride];
        int p = offs[d] + atomicAdd(&cur[d], 1);
        idx[p] = i;
    }
}

// ---------------- gather-reduce: act[row] += sum_{j in bucket(row)} upd[idx[j]]
__global__ __launch_bounds__(256) void k_reduce(const unsigned short* __restrict__ upd,
                                                const int* __restrict__ offs,
                                                const int* __restrict__ idx,
                                                unsigned short* __restrict__ act, int nRows){
    int gid = blockIdx.x * 256 + threadIdx.x;
    int row = gid >> 3;
    if (row >= nRows) return;
    int c8 = (gid & 7) * 8;
    int o = offs[row], e = offs[row + 1];
    float acc[8] = {};
    for (int j = o; j < e; ++j){
        s16x8 v = *(const s16x8*)&upd[(size_t)idx[j] * 64 + c8];
        #pragma unroll
        for (int q = 0; q < 8; ++q) acc[q] += bf2f((unsigned short)v[q]);
    }
    s16x8 a = *(s16x8*)&act[(size_t)row * 64 + c8];
    #pragma unroll
    for (int q = 0; q < 8; ++q) a[q] = (short)f2bf(bf2f((unsigned short)a[q]) + acc[q]);
    *(s16x8*)&act[(size_t)row * 64 + c8] = a;
}

// ---------------- atom conv: gathered gmlp over edges, W_out pre-applied, dense upd write
__global__ __launch_bounds__(256) void k_atom_conv(
    const unsigned short* __restrict__ atomBf, const unsigned short* __restrict__ bondBf,
    const unsigned short* __restrict__ bwagBf,
    const int* __restrict__ agraph, const int* __restrict__ d2u,
    const unsigned short* __restrict__ w1cT, const unsigned short* __restrict__ w1gT,
    const unsigned short* __restrict__ w2cT, const unsigned short* __restrict__ w2gT,
    const unsigned short* __restrict__ woT,
    const float* __restrict__ cb1, const float* __restrict__ cb2,
    const float* __restrict__ gb1, const float* __restrict__ gb2,
    unsigned short* __restrict__ upd)
{
    __shared__ unsigned short lds[64 * 216];   // overlay: ldsA(stride200) | HC,HG,V(stride72)
    __shared__ int ldsIdx[64];
    unsigned short* ldsA  = lds;
    unsigned short* ldsHC = lds;
    unsigned short* ldsHG = lds + 4608;
    unsigned short* ldsV  = lds + 9216;
    const int tid = threadIdx.x;
    const int r0  = blockIdx.x * 64;

    if (tid < 64) ldsIdx[tid] = d2u[r0 + tid];
    for (int c = tid; c < 64 * 24; c += 256){
        int row = c / 24, seg = c - row * 24;
        int e = r0 + row;
        int f8 = (seg & 7) * 8;
        const unsigned short* src;
        if (seg < 8)       src = atomBf + agraph[2 * e]     * 64 + f8;
        else if (seg < 16) src = bondBf + d2u[e]            * 64 + f8;
        else               src = atomBf + agraph[2 * e + 1] * 64 + f8;
        *(u32x4*)&ldsA[row * 200 + seg * 8] = *(const u32x4*)src;
    }
    __syncthreads();

    const int lane = tid & 63;
    const int r16  = lane & 15;
    const int grp  = lane >> 4;
    const int col  = (tid >> 6) * 16 + r16;

    s16x8 bc1[6], bg1[6], bc2[2], bg2[2], bo[2];
    #pragma unroll
    for (int kt = 0; kt < 6; ++kt){
        bc1[kt] = *(const s16x8*)&w1cT[col * 192 + kt * 32 + grp * 8];
        bg1[kt] = *(const s16x8*)&w1gT[col * 192 + kt * 32 + grp * 8];
    }
    #pragma unroll
    for (int kt = 0; kt < 2; ++kt){
        bc2[kt] = *(const s16x8*)&w2cT[col * 64 + kt * 32 + grp * 8];
        bg2[kt] = *(const s16x8*)&w2gT[col * 64 + kt * 32 + grp * 8];
        bo[kt]  = *(const s16x8*)&woT [col * 64 + kt * 32 + grp * 8];
    }

    f32x4 aC[4] = {}, aG[4] = {};
    #pragma unroll
    for (int kt = 0; kt < 6; ++kt){
        #pragma unroll
        for (int mt = 0; mt < 4; ++mt){
            s16x8 a = *(const s16x8*)&ldsA[(mt * 16 + r16) * 200 + kt * 32 + grp * 8];
            aC[mt] = __builtin_amdgcn_mfma_f32_16x16x32_bf16(a, bc1[kt], aC[mt], 0, 0, 0);
            aG[mt] = __builtin_amdgcn_mfma_f32_16x16x32_bf16(a, bg1[kt], aG[mt], 0, 0, 0);
        }
    }
    __syncthreads();   // ldsA dead; overlay becomes writable

    const float bC1 = cb1[col], bG1 = gb1[col];
    #pragma unroll
    for (int mt = 0; mt < 4; ++mt){
        #pragma unroll
        for (int j = 0; j < 4; ++j){
            int row = mt * 16 + grp * 4 + j;
            ldsHC[row * 72 + col] = f2bf(silu_(aC[mt][j] + bC1));
            ldsHG[row * 72 + col] = f2bf(silu_(aG[mt][j] + bG1));
        }
    }
    __syncthreads();

    f32x4 oC[4] = {}, oG[4] = {};
    #pragma unroll
    for (int kt = 0; kt < 2; ++kt){
        #pragma unroll
        for (int mt = 0; mt < 4; ++mt){
            s16x8 hc = *(const s16x8*)&ldsHC[(mt * 16 + r16) * 72 + kt * 32 + grp * 8];
            s16x8 hg = *(const s16x8*)&ldsHG[(mt * 16 + r16) * 72 + kt * 32 + grp * 8];
            oC[mt] = __builtin_amdgcn_mfma_f32_16x16x32_bf16(hc, bc2[kt], oC[mt], 0, 0, 0);
            oG[mt] = __builtin_amdgcn_mfma_f32_16x16x32_bf16(hg, bg2[kt], oG[mt], 0, 0, 0);
        }
    }
    const float bC2 = cb2[col], bG2 = gb2[col];
    #pragma unroll
    for (int mt = 0; mt < 4; ++mt){
        #pragma unroll
        for (int j = 0; j < 4; ++j){
            int row = mt * 16 + grp * 4 + j;
            float v = silu_(oC[mt][j] + bC2) * sigm_(oG[mt][j] + bG2);
            v *= bf2f(bwagBf[ldsIdx[row] * 64 + col]);
            ldsV[row * 72 + col] = f2bf(v);   // disjoint from HC/HG
        }
    }
    __syncthreads();

    f32x4 oD[4] = {};
    #pragma unroll
    for (int kt = 0; kt < 2; ++kt){
        #pragma unroll
        for (int mt = 0; mt < 4; ++mt){
            s16x8 a = *(const s16x8*)&ldsV[(mt * 16 + r16) * 72 + kt * 32 + grp * 8];
            oD[mt] = __builtin_amdgcn_mfma_f32_16x16x32_bf16(a, bo[kt], oD[mt], 0, 0, 0);
        }
    }
    #pragma unroll
    for (int mt = 0; mt < 4; ++mt){
        #pragma unroll
        for (int j = 0; j < 4; ++j){
            int row = mt * 16 + grp * 4 + j;
            upd[(size_t)(r0 + row) * 64 + col] = f2bf(oD[mt][j]);
        }
    }
}

// ---------------- bond conv: gathered gmlp over angles, W_out pre-applied, dense upd write
__global__ __launch_bounds__(256) void k_bond_conv(
    const unsigned short* __restrict__ atomBf, const unsigned short* __restrict__ bondBf,
    const unsigned short* __restrict__ angleBf, const unsigned short* __restrict__ bwbgBf,
    const int* __restrict__ bga, const int* __restrict__ bgb,
    const unsigned short* __restrict__ w1cT, const unsigned short* __restrict__ w1gT,
    const unsigned short* __restrict__ w2cT, const unsigned short* __restrict__ w2gT,
    const unsigned short* __restrict__ woT,
    const float* __restrict__ cb1, const float* __restrict__ cb2,
    const float* __restrict__ gb1, const float* __restrict__ gb2,
    unsigned short* __restrict__ upd)
{
    __shared__ unsigned short lds[64 * 264];   // overlay: ldsA(stride264) | HC,HG,V(stride72)
    __shared__ int ldsIdx[64];
    unsigned short* ldsA  = lds;
    unsigned short* ldsHC = lds;
    unsigned short* ldsHG = lds + 4608;
    unsigned short* ldsV  = lds + 9216;
    const int tid = threadIdx.x;
    const int r0  = blockIdx.x * 64;

    if (tid < 64) ldsIdx[tid] = bgb[2 * (r0 + tid)];
    for (int c = tid; c < 64 * 32; c += 256){
        int row = c >> 5, seg = c & 31;
        int a = r0 + row;
        int f8 = (seg & 7) * 8;
        const unsigned short* src;
        if (seg < 8)       src = bondBf  + bgb[2 * a]     * 64 + f8;
        else if (seg < 16) src = bondBf  + bgb[2 * a + 1] * 64 + f8;
        else if (seg < 24) src = angleBf + (size_t)a      * 64 + f8;
        else               src = atomBf  + bga[a]         * 64 + f8;
        *(u32x4*)&ldsA[row * 264 + seg * 8] = *(const u32x4*)src;
    }
    __syncthreads();

    const int lane = tid & 63;
    const int r16  = lane & 15;
    const int grp  = lane >> 4;
    const int col  = (tid >> 6) * 16 + r16;

    s16x8 bc1[8], bg1[8], bc2[2], bg2[2], bo[2];
    #pragma unroll
    for (int kt = 0; kt < 8; ++kt){
        bc1[kt] = *(const s16x8*)&w1cT[col * 256 + kt * 32 + grp * 8];
        bg1[kt] = *(const s16x8*)&w1gT[col * 256 + kt * 32 + grp * 8];
    }
    #pragma unroll
    for (int kt = 0; kt < 2; ++kt){
        bc2[kt] = *(const s16x8*)&w2cT[col * 64 + kt * 32 + grp * 8];
        bg2[kt] = *(const s16x8*)&w2gT[col * 64 + kt * 32 + grp * 8];
        bo[kt]  = *(const s16x8*)&woT [col * 64 + kt * 32 + grp * 8];
    }

    f32x4 aC[4] = {}, aG[4] = {};
    #pragma unroll
    for (int kt = 0; kt < 8; ++kt){
        #pragma unroll
        for (int mt = 0; mt < 4; ++mt){
            s16x8 a = *(const s16x8*)&ldsA[(mt * 16 + r16) * 264 + kt * 32 + grp * 8];
            aC[mt] = __builtin_amdgcn_mfma_f32_16x16x32_bf16(a, bc1[kt], aC[mt], 0, 0, 0);
            aG[mt] = __builtin_amdgcn_mfma_f32_16x16x32_bf16(a, bg1[kt], aG[mt], 0, 0, 0);
        }
    }
    __syncthreads();

    const float bC1 = cb1[col], bG1 = gb1[col];
    #pragma unroll
    for (int mt = 0; mt < 4; ++mt){
        #pragma unroll
        for (int j = 0; j < 4; ++j){
            int row = mt * 16 + grp * 4 + j;
            ldsHC[row * 72 + col] = f2bf(silu_(aC[mt][j] + bC1));
            ldsHG[row * 72 + col] = f2bf(silu_(aG[mt][j] + bG1));
        }
    }
    __syncthreads();

    f32x4 oC[4] = {}, oG[4] = {};
    #pragma unroll
    for (int kt = 0; kt < 2; ++kt){
        #pragma unroll
        for (int mt = 0; mt < 4; ++mt){
            s16x8 hc = *(const s16x8*)&ldsHC[(mt * 16 + r16) * 72 + kt * 32 + grp * 8];
            s16x8 hg = *(const s16x8*)&ldsHG[(mt * 16 + r16) * 72 + kt * 32 + grp * 8];
            oC[mt] = __builtin_amdgcn_mfma_f32_16x16x32_bf16(hc, bc2[kt], oC[mt], 0, 0, 0);
            oG[mt] = __builtin_amdgcn_mfma_f32_16x16x32_bf16(hg, bg2[kt], oG[mt], 0, 0, 0);
        }
    }
    const float bC2 = cb2[col], bG2 = gb2[col];
    #pragma unroll
    for (int mt = 0; mt < 4; ++mt){
        #pragma unroll
        for (int j = 0; j < 4; ++j){
            int row = mt * 16 + grp * 4 + j;
            float v = silu_(oC[mt][j] + bC2) * sigm_(oG[mt][j] + bG2);
            v *= bf2f(bwbgBf[ldsIdx[row] * 64 + col]);
            ldsV[row * 72 + col] = f2bf(v);
        }
    }
    __syncthreads();

    f32x4 oD[4] = {};
    #pragma unroll
    for (int kt = 0; kt < 2; ++kt){
        #pragma unroll
        for (int mt = 0; mt < 4; ++mt){
            s16x8 a = *(const s16x8*)&ldsV[(mt * 16 + r16) * 72 + kt * 32 + grp * 8];
            oD[mt] = __builtin_amdgcn_mfma_f32_16x16x32_bf16(a, bo[kt], oD[mt], 0, 0, 0);
        }
    }
    #pragma unroll
    for (int mt = 0; mt < 4; ++mt){
        #pragma unroll
        for (int j = 0; j < 4; ++j){
            int row = mt * 16 + grp * 4 + j;
            upd[(size_t)(r0 + row) * 64 + col] = f2bf(oD[mt][j]);
        }
    }
}

// ---------------- angle update (single gated layer), in-place residual on angleBf
__global__ __launch_bounds__(256) void k_angle(
    const unsigned short* __restrict__ atomBf, const unsigned short* __restrict__ bondBf,
    unsigned short* __restrict__ angleBf,
    const int* __restrict__ bga, const int* __restrict__ bgb,
    const unsigned short* __restrict__ wcT, const unsigned short* __restrict__ wgT,
    const float* __restrict__ cb, const float* __restrict__ gb)
{
    __shared__ unsigned short ldsA[64 * 264];
    const int tid = threadIdx.x;
    const int r0  = blockIdx.x * 64;

    for (int c = tid; c < 64 * 32; c += 256){
        int row = c >> 5, seg = c & 31;
        int a = r0 + row;
        int f8 = (seg & 7) * 8;
        const unsigned short* src;
        if (seg < 8)       src = bondBf  + bgb[2 * a]     * 64 + f8;
        else if (seg < 16) src = bondBf  + bgb[2 * a + 1] * 64 + f8;
        else if (seg < 24) src = angleBf + (size_t)a      * 64 + f8;
        else               src = atomBf  + bga[a]         * 64 + f8;
        *(u32x4*)&ldsA[row * 264 + seg * 8] = *(const u32x4*)src;
    }
    __syncthreads();

    const int lane = tid & 63;
    const int r16  = lane & 15;
    const int grp  = lane >> 4;
    const int col  = (tid >> 6) * 16 + r16;

    s16x8 bc[8], bg_[8];
    #pragma unroll
    for (int kt = 0; kt < 8; ++kt){
        bc[kt]  = *(const s16x8*)&wcT[col * 256 + kt * 32 + grp * 8];
        bg_[kt] = *(const s16x8*)&wgT[col * 256 + kt * 32 + grp * 8];
    }
    f32x4 aC[4] = {}, aG[4] = {};
    #pragma unroll
    for (int kt = 0; kt < 8; ++kt){
        #pragma unroll
        for (int mt = 0; mt < 4; ++mt){
            s16x8 a = *(const s16x8*)&ldsA[(mt * 16 + r16) * 264 + kt * 32 + grp * 8];
            aC[mt] = __builtin_amdgcn_mfma_f32_16x16x32_bf16(a, bc[kt],  aC[mt], 0, 0, 0);
            aG[mt] = __builtin_amdgcn_mfma_f32_16x16x32_bf16(a, bg_[kt], aG[mt], 0, 0, 0);
        }
    }
    const float bC = cb[col], bG = gb[col];
    #pragma unroll
    for (int mt = 0; mt < 4; ++mt){
        #pragma unroll
        for (int j = 0; j < 4; ++j){
            int row = mt * 16 + grp * 4 + j;
            int a = r0 + row;
            float oldv = bf2f(ldsA[row * 264 + 128 + col]);
            float v = silu_(aC[mt][j] + bC) * sigm_(aG[mt][j] + bG);
            angleBf[(size_t)a * 64 + col] = f2bf(oldv + v);
        }
    }
}

// ---------------- readout MLP + segmented sum (wave per atom row)
__global__ __launch_bounds__(256) void k_readout(
    const unsigned short* __restrict__ atomBf, const int* __restrict__ owners,
    const float* __restrict__ w1, const float* __restrict__ b1,
    const float* __restrict__ w2, const float* __restrict__ b2,
    const float* __restrict__ w3, const float* __restrict__ b3,
    float* __restrict__ esum, float* __restrict__ cnt)
{
    int gid  = blockIdx.x * 256 + threadIdx.x;
    int n    = gid >> 6;
    int lane = threadIdx.x & 63;
    float a = bf2f(atomBf[n * 64 + lane]);
    float acc = b1[lane];
    #pragma unroll
    for (int k = 0; k < 64; ++k) acc += __shfl(a, k) * w1[k * 64 + lane];
    float h = silu_(acc);
    acc = b2[lane];
    #pragma unroll
    for (int k = 0; k < 64; ++k) acc += __shfl(h, k) * w2[k * 64 + lane];
    h = silu_(acc);
    float p = h * w3[lane];
    #pragma unroll
    for (int off = 32; off > 0; off >>= 1) p += __shfl_xor(p, off);
    if (lane == 0){
        atomicAdd(&esum[owners[n]], p + b3[0]);
        atomicAdd(&cnt[owners[n]], 1.0f);
    }
}

__global__ void k_final(const float* __restrict__ esum, const float* __restrict__ cnt,
                        float* __restrict__ out){
    int i = threadIdx.x;
    if (i < 128) out[i] = esum[i] / fmaxf(cnt[i], 1.0f);
}

extern "C" void kernel_launch(void* const* d_in, const int* in_sizes, int n_in,
                              void* d_out, int out_size, void* d_ws, size_t ws_size,
                              hipStream_t stream)
{
    (void)in_sizes; (void)n_in; (void)out_size; (void)ws_size;
    const int N_ATOMS = 8192, N_UND = 65536, N_DIR = 131072, N_ANG = 262144;

    const int*   atomic_numbers = (const int*)  d_in[0];
    const float* bb_ag  = (const float*)d_in[1];
    const float* bb_bg  = (const float*)d_in[2];
    const float* ang_b  = (const float*)d_in[3];
    const int*   agraph = (const int*)  d_in[4];
    const int*   d2u    = (const int*)  d_in[5];
    const int*   bga    = (const int*)  d_in[6];
    const int*   bgb    = (const int*)  d_in[7];
    const int*   owners = (const int*)  d_in[8];
    const float* emb    = (const float*)d_in[9];
    const float* Wb     = (const float*)d_in[10];
    const float* Wa     = (const float*)d_in[11];
    const float* Wbwag  = (const float*)d_in[12];
    const float* Wbwbg  = (const float*)d_in[13];
    const float* ac_cw1 = (const float*)d_in[14];
    const float* ac_cb1 = (const float*)d_in[15];
    const float* ac_cw2 = (const float*)d_in[16];
    const float* ac_cb2 = (const float*)d_in[17];
    const float* ac_gw1 = (const float*)d_in[18];
    const float* ac_gb1 = (const float*)d_in[19];
    const float* ac_gw2 = (const float*)d_in[20];
    const float* ac_gb2 = (const float*)d_in[21];
    const float* ac_out = (const float*)d_in[22];
    const float* bc_cw1 = (const float*)d_in[23];
    const float* bc_cb1 = (const float*)d_in[24];
    const float* bc_cw2 = (const float*)d_in[25];
    const float* bc_cb2 = (const float*)d_in[26];
    const float* bc_gw1 = (const float*)d_in[27];
    const float* bc_gb1 = (const float*)d_in[28];
    const float* bc_gw2 = (const float*)d_in[29];
    const float* bc_gb2 = (const float*)d_in[30];
    const float* bc_out = (const float*)d_in[31];
    const float* an_cw  = (const float*)d_in[32];
    const float* an_cb  = (const float*)d_in[33];
    const float* an_gw  = (const float*)d_in[34];
    const float* an_gb  = (const float*)d_in[35];
    const float* ro_w1  = (const float*)d_in[36];
    const float* ro_b1  = (const float*)d_in[37];
    const float* ro_w2  = (const float*)d_in[38];
    const float* ro_b2  = (const float*)d_in[39];
    const float* ro_w3  = (const float*)d_in[40];
    const float* ro_b3  = (const float*)d_in[41];

    char* ws = (char*)d_ws;
    size_t off = 0;
    auto alloc = [&](size_t bytes) -> void* {
        void* p = ws + off;
        off = (off + bytes + 255) & ~(size_t)255;
        return p;
    };
    unsigned short* atomBf  = (unsigned short*)alloc((size_t)N_ATOMS * 64 * 2);
    unsigned short* bondBf  = (unsigned short*)alloc((size_t)N_UND   * 64 * 2);
    unsigned short* angleBf = (unsigned short*)alloc((size_t)N_ANG   * 64 * 2);
    unsigned short* bwagBf  = (unsigned short*)alloc((size_t)N_UND   * 64 * 2);
    unsigned short* bwbgBf  = (unsigned short*)alloc((size_t)N_UND   * 64 * 2);
    unsigned short* updBuf  = (unsigned short*)alloc((size_t)N_ANG   * 64 * 2);  // shared atom/bond
    float* esum   = (float*)alloc(128 * 4);
    float* cnt    = (float*)alloc(128 * 4);
    int* offsA = (int*)alloc((N_ATOMS + 1) * 4);
    int* curA  = (int*)alloc(N_ATOMS * 4);
    int* idxA  = (int*)alloc((size_t)N_DIR * 4);
    int* offsB = (int*)alloc((N_UND + 1) * 4);
    int* curB  = (int*)alloc(N_UND * 4);
    int* idxB  = (int*)alloc((size_t)N_ANG * 4);
    unsigned short* acw1cT = (unsigned short*)alloc((size_t)4 * 64 * 192 * 2);
    unsigned short* acw1gT = (unsigned short*)alloc((size_t)4 * 64 * 192 * 2);
    unsigned short* acw2cT = (unsigned short*)alloc((size_t)4 * 64 * 64 * 2);
    unsigned short* acw2gT = (unsigned short*)alloc((size_t)4 * 64 * 64 * 2);
    unsigned short* acoT   = (unsigned short*)alloc((size_t)4 * 64 * 64 * 2);
    unsigned short* bcw1cT = (unsigned short*)alloc((size_t)3 * 64 * 256 * 2);
    unsigned short* bcw1gT = (unsigned short*)alloc((size_t)3 * 64 * 256 * 2);
    unsigned short* bcw2cT = (unsigned short*)alloc((size_t)3 * 64 * 64 * 2);
    unsigned short* bcw2gT = (unsigned short*)alloc((size_t)3 * 64 * 64 * 2);
    unsigned short* bcoT   = (unsigned short*)alloc((size_t)3 * 64 * 64 * 2);
    unsigned short* anwcT  = (unsigned short*)alloc((size_t)3 * 64 * 256 * 2);
    unsigned short* anwgT  = (unsigned short*)alloc((size_t)3 * 64 * 256 * 2);

    auto tc = [&](const float* src, unsigned short* dst, int B, int K){
        int total = B * K * 64;
        k_transconv<<<(total + 255) / 256, 256, 0, stream>>>(src, dst, K, total);
    };
    tc(ac_cw1, acw1cT, 4, 192);  tc(ac_gw1, acw1gT, 4, 192);
    tc(ac_cw2, acw2cT, 4, 64);   tc(ac_gw2, acw2gT, 4, 64);
    tc(ac_out, acoT,   4, 64);
    tc(bc_cw1, bcw1cT, 3, 256);  tc(bc_gw1, bcw1gT, 3, 256);
    tc(bc_cw2, bcw2cT, 3, 64);   tc(bc_gw2, bcw2gT, 3, 64);
    tc(bc_out, bcoT,   3, 64);
    tc(an_cw,  anwcT,  3, 256);  tc(an_gw,  anwgT,  3, 256);

    k_embed<<<N_ATOMS * 64 / 256, 256, 0, stream>>>(emb, atomic_numbers, atomBf);
    k_smallmm<<<N_UND * 64 / 256, 256, 0, stream>>>(bb_ag, Wb,    bondBf);
    k_smallmm<<<N_ANG * 64 / 256, 256, 0, stream>>>(ang_b, Wa,    angleBf);
    k_smallmm<<<N_UND * 64 / 256, 256, 0, stream>>>(bb_ag, Wbwag, bwagBf);
    k_smallmm<<<N_UND * 64 / 256, 256, 0, stream>>>(bb_bg, Wbwbg, bwbgBf);

    // CSR build (graph static across iterations)
    hipMemsetAsync(curA, 0, N_ATOMS * 4, stream);
    k_count<<<(N_DIR + 255) / 256, 256, 0, stream>>>(agraph, 2, N_DIR, curA);
    k_scan<<<1, 1024, 0, stream>>>(curA, offsA, N_ATOMS);
    hipMemsetAsync(curA, 0, N_ATOMS * 4, stream);
    k_fill<<<(N_DIR + 255) / 256, 256, 0, stream>>>(agraph, 2, N_DIR, offsA, curA, idxA);

    hipMemsetAsync(curB, 0, N_UND * 4, stream);
    k_count<<<(N_ANG + 255) / 256, 256, 0, stream>>>(bgb, 2, N_ANG, curB);
    k_scan<<<1, 1024, 0, stream>>>(curB, offsB, N_UND);
    hipMemsetAsync(curB, 0, N_UND * 4, stream);
    k_fill<<<(N_ANG + 255) / 256, 256, 0, stream>>>(bgb, 2, N_ANG, offsB, curB, idxB);

    for (int i = 0; i < 4; ++i){
        k_atom_conv<<<N_DIR / 64, 256, 0, stream>>>(
            atomBf, bondBf, bwagBf, agraph, d2u,
            acw1cT + (size_t)i * 64 * 192, acw1gT + (size_t)i * 64 * 192,
            acw2cT + (size_t)i * 64 * 64,  acw2gT + (size_t)i * 64 * 64,
            acoT   + (size_t)i * 64 * 64,
            ac_cb1 + i * 64, ac_cb2 + i * 64, ac_gb1 + i * 64, ac_gb2 + i * 64, updBuf);
        k_reduce<<<N_ATOMS * 8 / 256, 256, 0, stream>>>(updBuf, offsA, idxA, atomBf, N_ATOMS);
        if (i == 3) break;
        k_bond_conv<<<N_ANG / 64, 256, 0, stream>>>(
            atomBf, bondBf, angleBf, bwbgBf, bga, bgb,
            bcw1cT + (size_t)i * 64 * 256, bcw1gT + (size_t)i * 64 * 256,
            bcw2cT + (size_t)i * 64 * 64,  bcw2gT + (size_t)i * 64 * 64,
            bcoT   + (size_t)i * 64 * 64,
            bc_cb1 + i * 64, bc_cb2 + i * 64, bc_gb1 + i * 64, bc_gb2 + i * 64, updBuf);
        k_reduce<<<N_UND * 8 / 256, 256, 0, stream>>>(updBuf, offsB, idxB, bondBf, N_UND);
        k_angle<<<N_ANG / 64, 256, 0, stream>>>(
            atomBf, bondBf, angleBf, bga, bgb,
            anwcT + (size_t)i * 64 * 256, anwgT + (size_t)i * 64 * 256,
            an_cb + i * 64, an_gb + i * 64);
    }

    hipMemsetAsync(esum, 0, 128 * 4, stream);
    hipMemsetAsync(cnt,  0, 128 * 4, stream);
    k_readout<<<N_ATOMS * 64 / 256, 256, 0, stream>>>(
        atomBf, owners, ro_w1, ro_b1, ro_w2, ro_b2, ro_w3, ro_b3, esum, cnt);
    k_final<<<1, 128, 0, stream>>>(esum, cnt, (float*)d_out);
}

// Round 3
// 1007.682 us; speedup vs baseline: 1.3092x; 1.0882x over previous
//
#include <hip/hip_runtime.h>
#include <hip/hip_bf16.h>

typedef float f32x4 __attribute__((ext_vector_type(4)));
typedef short s16x8 __attribute__((ext_vector_type(8)));
typedef unsigned int u32x4 __attribute__((ext_vector_type(4)));

#define DEV static __device__ __forceinline__

DEV unsigned short f2bf(float x){
    unsigned u = __builtin_bit_cast(unsigned, x);
    u += 0x7FFFu + ((u >> 16) & 1u);
    return (unsigned short)(u >> 16);
}
DEV float bf2f(unsigned short h){
    unsigned u = ((unsigned)h) << 16;
    return __builtin_bit_cast(float, u);
}
DEV float sigm_(float x){ return __builtin_amdgcn_rcpf(1.0f + __expf(-x)); }
DEV float silu_(float x){ return x * sigm_(x); }

// ---------------- weight transpose + convert:  src [B][K][64] f32 -> dst [B][64][K] bf16
__global__ __launch_bounds__(256) void k_transconv(const float* __restrict__ src,
                                                   unsigned short* __restrict__ dst,
                                                   int K, int total){
    int gid = blockIdx.x * 256 + threadIdx.x;
    if (gid >= total) return;
    int kn  = K * 64;
    int b   = gid / kn;
    int rem = gid - b * kn;
    int k   = rem >> 6, n = rem & 63;
    dst[b * kn + n * K + k] = f2bf(src[gid]);
}

// ---------------- atom embedding gather
__global__ __launch_bounds__(256) void k_embed(const float* __restrict__ emb,
                                               const int* __restrict__ z,
                                               unsigned short* __restrict__ out){
    int gid = blockIdx.x * 256 + threadIdx.x;
    int n = gid >> 6, f = gid & 63;
    out[gid] = f2bf(emb[z[n] * 64 + f]);
}

// ---------------- bases[rows][9] @ W[9][64] -> bf16 out[rows][64]
__global__ __launch_bounds__(256) void k_smallmm(const float* __restrict__ bases,
                                                 const float* __restrict__ W,
                                                 unsigned short* __restrict__ out){
    int gid = blockIdx.x * 256 + threadIdx.x;
    int r = gid >> 6, f = gid & 63;
    const float* b = bases + r * 9;
    float acc = 0.f;
    #pragma unroll
    for (int k = 0; k < 9; ++k) acc += b[k] * W[k * 64 + f];
    out[gid] = f2bf(acc);
}

// ---------------- CSR build helpers
__global__ void k_count(const int* __restrict__ dst, int stride, int n, int* __restrict__ cnt){
    int i = blockIdx.x * 256 + threadIdx.x;
    if (i < n) atomicAdd(&cnt[dst[(size_t)i * stride]], 1);
}

__global__ __launch_bounds__(1024) void k_scan(const int* __restrict__ cnt,
                                               int* __restrict__ offs, int n){
    __shared__ int part[1024];
    int t = threadIdx.x;
    int chunk = n >> 10;
    int base = t * chunk;
    int s = 0;
    for (int j = 0; j < chunk; ++j) s += cnt[base + j];
    part[t] = s;
    __syncthreads();
    for (int d = 1; d < 1024; d <<= 1){
        int v = (t >= d) ? part[t - d] : 0;
        __syncthreads();
        part[t] += v;
        __syncthreads();
    }
    int run = (t == 0) ? 0 : part[t - 1];
    for (int j = 0; j < chunk; ++j){
        offs[base + j] = run;
        run += cnt[base + j];
    }
    if (t == 1023) offs[n] = run;
}

__global__ void k_fill(const int* __restrict__ dst, int stride, int n,
                       const int* __restrict__ offs, int* __restrict__ cur,
                       int* __restrict__ idx){
    int i = blockIdx.x * 256 + threadIdx.x;
    if (i < n){
        int d = dst[(size_t)i * stride];
        int p = offs[d] + atomicAdd(&cur[d], 1);
        idx[p] = i;
    }
}

// ---------------- gather-reduce: act[row] += sum_{j in bucket(row)} upd[idx[j]]
__global__ __launch_bounds__(256) void k_reduce(const unsigned short* __restrict__ upd,
                                                const int* __restrict__ offs,
                                                const int* __restrict__ idx,
                                                unsigned short* __restrict__ act, int nRows){
    int gid = blockIdx.x * 256 + threadIdx.x;
    int row = gid >> 3;
    if (row >= nRows) return;
    int c8 = (gid & 7) * 8;
    int o = offs[row], e = offs[row + 1];
    float acc[8] = {};
    for (int j = o; j < e; ++j){
        s16x8 v = *(const s16x8*)&upd[(size_t)idx[j] * 64 + c8];
        #pragma unroll
        for (int q = 0; q < 8; ++q) acc[q] += bf2f((unsigned short)v[q]);
    }
    s16x8 a = *(s16x8*)&act[(size_t)row * 64 + c8];
    #pragma unroll
    for (int q = 0; q < 8; ++q) a[q] = (short)f2bf(bf2f((unsigned short)a[q]) + acc[q]);
    *(s16x8*)&act[(size_t)row * 64 + c8] = a;
}

#define MFMA16(a,b,c) __builtin_amdgcn_mfma_f32_16x16x32_bf16(a,b,c,0,0,0)

// ---------------- atom conv: gathered gmlp over edges, W_out pre-applied, dense upd write
__global__ __launch_bounds__(256, 4) void k_atom_conv(
    const unsigned short* __restrict__ atomBf, const unsigned short* __restrict__ bondBf,
    const unsigned short* __restrict__ bwagBf,
    const int* __restrict__ agraph, const int* __restrict__ d2u,
    const unsigned short* __restrict__ w1cT, const unsigned short* __restrict__ w1gT,
    const unsigned short* __restrict__ w2cT, const unsigned short* __restrict__ w2gT,
    const unsigned short* __restrict__ woT,
    const float* __restrict__ cb1, const float* __restrict__ cb2,
    const float* __restrict__ gb1, const float* __restrict__ gb2,
    unsigned short* __restrict__ upd)
{
    __shared__ unsigned short lds[14208];   // overlay: ldsA [64][200] | HC,HG,V [64][74]
    __shared__ int ldsIdx[64];
    unsigned short* ldsA  = lds;
    unsigned short* ldsHC = lds;
    unsigned short* ldsHG = lds + 4736;
    unsigned short* ldsV  = lds + 9472;
    const int tid = threadIdx.x;
    const int r0  = blockIdx.x * 64;

    {   // stage: thread (srow, q) copies one 128B source row
        const int srow = tid >> 2, q = tid & 3;
        int e = r0 + srow;
        if (q < 3){
            const unsigned short* src;
            if (q == 0)      src = atomBf + (size_t)agraph[2 * e] * 64;
            else if (q == 1){ int u = d2u[e]; ldsIdx[srow] = u; src = bondBf + (size_t)u * 64; }
            else             src = atomBf + (size_t)agraph[2 * e + 1] * 64;
            #pragma unroll
            for (int j = 0; j < 8; ++j)
                *(u32x4*)&ldsA[srow * 200 + q * 64 + j * 8] = *(const u32x4*)(src + j * 8);
        }
    }
    __syncthreads();

    const int lane = tid & 63;
    const int r16  = lane & 15;
    const int grp  = lane >> 4;
    const int col  = (tid >> 6) * 16 + r16;

    // issue bw gather early; consumed only in the epilogue
    unsigned short bwv[16];
    #pragma unroll
    for (int mt = 0; mt < 4; ++mt)
        #pragma unroll
        for (int j = 0; j < 4; ++j)
            bwv[mt * 4 + j] = bwagBf[(size_t)ldsIdx[mt * 16 + grp * 4 + j] * 64 + col];

    f32x4 aC[4] = {}, aG[4] = {};
    #pragma unroll
    for (int kt = 0; kt < 6; ++kt){
        s16x8 bc = *(const s16x8*)&w1cT[col * 192 + kt * 32 + grp * 8];
        s16x8 bg = *(const s16x8*)&w1gT[col * 192 + kt * 32 + grp * 8];
        #pragma unroll
        for (int mt = 0; mt < 4; ++mt){
            s16x8 a = *(const s16x8*)&ldsA[(mt * 16 + r16) * 200 + kt * 32 + grp * 8];
            aC[mt] = MFMA16(a, bc, aC[mt]);
            aG[mt] = MFMA16(a, bg, aG[mt]);
        }
    }
    __syncthreads();   // ldsA dead; overlay writable

    const float bC1 = cb1[col], bG1 = gb1[col];
    #pragma unroll
    for (int mt = 0; mt < 4; ++mt){
        #pragma unroll
        for (int j = 0; j < 4; ++j){
            int row = mt * 16 + grp * 4 + j;
            ldsHC[row * 74 + col] = f2bf(silu_(aC[mt][j] + bC1));
            ldsHG[row * 74 + col] = f2bf(silu_(aG[mt][j] + bG1));
        }
    }
    __syncthreads();

    f32x4 oC[4] = {}, oG[4] = {};
    #pragma unroll
    for (int kt = 0; kt < 2; ++kt){
        s16x8 bc = *(const s16x8*)&w2cT[col * 64 + kt * 32 + grp * 8];
        s16x8 bg = *(const s16x8*)&w2gT[col * 64 + kt * 32 + grp * 8];
        #pragma unroll
        for (int mt = 0; mt < 4; ++mt){
            s16x8 hc = *(const s16x8*)&ldsHC[(mt * 16 + r16) * 74 + kt * 32 + grp * 8];
            s16x8 hg = *(const s16x8*)&ldsHG[(mt * 16 + r16) * 74 + kt * 32 + grp * 8];
            oC[mt] = MFMA16(hc, bc, oC[mt]);
            oG[mt] = MFMA16(hg, bg, oG[mt]);
        }
    }
    const float bC2 = cb2[col], bG2 = gb2[col];
    #pragma unroll
    for (int mt = 0; mt < 4; ++mt){
        #pragma unroll
        for (int j = 0; j < 4; ++j){
            int row = mt * 16 + grp * 4 + j;
            float v = silu_(oC[mt][j] + bC2) * sigm_(oG[mt][j] + bG2);
            v *= bf2f(bwv[mt * 4 + j]);
            ldsV[row * 74 + col] = f2bf(v);
        }
    }
    __syncthreads();

    f32x4 oD[4] = {};
    #pragma unroll
    for (int kt = 0; kt < 2; ++kt){
        s16x8 bo = *(const s16x8*)&woT[col * 64 + kt * 32 + grp * 8];
        #pragma unroll
        for (int mt = 0; mt < 4; ++mt){
            s16x8 a = *(const s16x8*)&ldsV[(mt * 16 + r16) * 74 + kt * 32 + grp * 8];
            oD[mt] = MFMA16(a, bo, oD[mt]);
        }
    }
    #pragma unroll
    for (int mt = 0; mt < 4; ++mt){
        #pragma unroll
        for (int j = 0; j < 4; ++j){
            int row = mt * 16 + grp * 4 + j;
            upd[(size_t)(r0 + row) * 64 + col] = f2bf(oD[mt][j]);
        }
    }
}

// ---------------- bond conv: gathered gmlp over angles, W_out pre-applied, dense upd write
__global__ __launch_bounds__(256, 4) void k_bond_conv(
    const unsigned short* __restrict__ atomBf, const unsigned short* __restrict__ bondBf,
    const unsigned short* __restrict__ angleBf, const unsigned short* __restrict__ bwbgBf,
    const int* __restrict__ bga, const int* __restrict__ bgb,
    const unsigned short* __restrict__ w1cT, const unsigned short* __restrict__ w1gT,
    const unsigned short* __restrict__ w2cT, const unsigned short* __restrict__ w2gT,
    const unsigned short* __restrict__ woT,
    const float* __restrict__ cb1, const float* __restrict__ cb2,
    const float* __restrict__ gb1, const float* __restrict__ gb2,
    unsigned short* __restrict__ upd)
{
    __shared__ unsigned short lds[16896];   // overlay: ldsA [64][264] | HC,HG,V [64][74]
    __shared__ int ldsIdx[64];
    unsigned short* ldsA  = lds;
    unsigned short* ldsHC = lds;
    unsigned short* ldsHG = lds + 4736;
    unsigned short* ldsV  = lds + 9472;
    const int tid = threadIdx.x;
    const int r0  = blockIdx.x * 64;

    {
        const int srow = tid >> 2, q = tid & 3;
        int a = r0 + srow;
        const unsigned short* src;
        if (q == 0){ int2 bb = *(const int2*)&bgb[2 * a]; ldsIdx[srow] = bb.x;
                     src = bondBf + (size_t)bb.x * 64; }
        else if (q == 1){ src = bondBf  + (size_t)bgb[2 * a + 1] * 64; }
        else if (q == 2){ src = angleBf + (size_t)a * 64; }
        else            { src = atomBf  + (size_t)bga[a] * 64; }
        #pragma unroll
        for (int j = 0; j < 8; ++j)
            *(u32x4*)&ldsA[srow * 264 + q * 64 + j * 8] = *(const u32x4*)(src + j * 8);
    }
    __syncthreads();

    const int lane = tid & 63;
    const int r16  = lane & 15;
    const int grp  = lane >> 4;
    const int col  = (tid >> 6) * 16 + r16;

    unsigned short bwv[16];
    #pragma unroll
    for (int mt = 0; mt < 4; ++mt)
        #pragma unroll
        for (int j = 0; j < 4; ++j)
            bwv[mt * 4 + j] = bwbgBf[(size_t)ldsIdx[mt * 16 + grp * 4 + j] * 64 + col];

    f32x4 aC[4] = {}, aG[4] = {};
    #pragma unroll
    for (int kt = 0; kt < 8; ++kt){
        s16x8 bc = *(const s16x8*)&w1cT[col * 256 + kt * 32 + grp * 8];
        s16x8 bg = *(const s16x8*)&w1gT[col * 256 + kt * 32 + grp * 8];
        #pragma unroll
        for (int mt = 0; mt < 4; ++mt){
            s16x8 a = *(const s16x8*)&ldsA[(mt * 16 + r16) * 264 + kt * 32 + grp * 8];
            aC[mt] = MFMA16(a, bc, aC[mt]);
            aG[mt] = MFMA16(a, bg, aG[mt]);
        }
    }
    __syncthreads();

    const float bC1 = cb1[col], bG1 = gb1[col];
    #pragma unroll
    for (int mt = 0; mt < 4; ++mt){
        #pragma unroll
        for (int j = 0; j < 4; ++j){
            int row = mt * 16 + grp * 4 + j;
            ldsHC[row * 74 + col] = f2bf(silu_(aC[mt][j] + bC1));
            ldsHG[row * 74 + col] = f2bf(silu_(aG[mt][j] + bG1));
        }
    }
    __syncthreads();

    f32x4 oC[4] = {}, oG[4] = {};
    #pragma unroll
    for (int kt = 0; kt < 2; ++kt){
        s16x8 bc = *(const s16x8*)&w2cT[col * 64 + kt * 32 + grp * 8];
        s16x8 bg = *(const s16x8*)&w2gT[col * 64 + kt * 32 + grp * 8];
        #pragma unroll
        for (int mt = 0; mt < 4; ++mt){
            s16x8 hc = *(const s16x8*)&ldsHC[(mt * 16 + r16) * 74 + kt * 32 + grp * 8];
            s16x8 hg = *(const s16x8*)&ldsHG[(mt * 16 + r16) * 74 + kt * 32 + grp * 8];
            oC[mt] = MFMA16(hc, bc, oC[mt]);
            oG[mt] = MFMA16(hg, bg, oG[mt]);
        }
    }
    const float bC2 = cb2[col], bG2 = gb2[col];
    #pragma unroll
    for (int mt = 0; mt < 4; ++mt){
        #pragma unroll
        for (int j = 0; j < 4; ++j){
            int row = mt * 16 + grp * 4 + j;
            float v = silu_(oC[mt][j] + bC2) * sigm_(oG[mt][j] + bG2);
            v *= bf2f(bwv[mt * 4 + j]);
            ldsV[row * 74 + col] = f2bf(v);
        }
    }
    __syncthreads();

    f32x4 oD[4] = {};
    #pragma unroll
    for (int kt = 0; kt < 2; ++kt){
        s16x8 bo = *(const s16x8*)&woT[col * 64 + kt * 32 + grp * 8];
        #pragma unroll
        for (int mt = 0; mt < 4; ++mt){
            s16x8 a = *(const s16x8*)&ldsV[(mt * 16 + r16) * 74 + kt * 32 + grp * 8];
            oD[mt] = MFMA16(a, bo, oD[mt]);
        }
    }
    #pragma unroll
    for (int mt = 0; mt < 4; ++mt){
        #pragma unroll
        for (int j = 0; j < 4; ++j){
            int row = mt * 16 + grp * 4 + j;
            upd[(size_t)(r0 + row) * 64 + col] = f2bf(oD[mt][j]);
        }
    }
}

// ---------------- angle update (single gated layer), in-place residual on angleBf
__global__ __launch_bounds__(256, 4) void k_angle(
    const unsigned short* __restrict__ atomBf, const unsigned short* __restrict__ bondBf,
    unsigned short* __restrict__ angleBf,
    const int* __restrict__ bga, const int* __restrict__ bgb,
    const unsigned short* __restrict__ wcT, const unsigned short* __restrict__ wgT,
    const float* __restrict__ cb, const float* __restrict__ gb)
{
    __shared__ unsigned short ldsA[64 * 264];
    const int tid = threadIdx.x;
    const int r0  = blockIdx.x * 64;

    {
        const int srow = tid >> 2, q = tid & 3;
        int a = r0 + srow;
        const unsigned short* src;
        if (q == 0)      src = bondBf  + (size_t)bgb[2 * a] * 64;
        else if (q == 1) src = bondBf  + (size_t)bgb[2 * a + 1] * 64;
        else if (q == 2) src = angleBf + (size_t)a * 64;
        else             src = atomBf  + (size_t)bga[a] * 64;
        #pragma unroll
        for (int j = 0; j < 8; ++j)
            *(u32x4*)&ldsA[srow * 264 + q * 64 + j * 8] = *(const u32x4*)(src + j * 8);
    }
    __syncthreads();

    const int lane = tid & 63;
    const int r16  = lane & 15;
    const int grp  = lane >> 4;
    const int col  = (tid >> 6) * 16 + r16;

    f32x4 aC[4] = {}, aG[4] = {};
    #pragma unroll
    for (int kt = 0; kt < 8; ++kt){
        s16x8 bc = *(const s16x8*)&wcT[col * 256 + kt * 32 + grp * 8];
        s16x8 bg = *(const s16x8*)&wgT[col * 256 + kt * 32 + grp * 8];
        #pragma unroll
        for (int mt = 0; mt < 4; ++mt){
            s16x8 a = *(const s16x8*)&ldsA[(mt * 16 + r16) * 264 + kt * 32 + grp * 8];
            aC[mt] = MFMA16(a, bc, aC[mt]);
            aG[mt] = MFMA16(a, bg, aG[mt]);
        }
    }
    const float bC = cb[col], bG = gb[col];
    #pragma unroll
    for (int mt = 0; mt < 4; ++mt){
        #pragma unroll
        for (int j = 0; j < 4; ++j){
            int row = mt * 16 + grp * 4 + j;
            int a = r0 + row;
            float oldv = bf2f(ldsA[row * 264 + 128 + col]);
            float v = silu_(aC[mt][j] + bC) * sigm_(aG[mt][j] + bG);
            angleBf[(size_t)a * 64 + col] = f2bf(oldv + v);
        }
    }
}

// ---------------- readout MLP + segmented sum (wave per atom row)
__global__ __launch_bounds__(256) void k_readout(
    const unsigned short* __restrict__ atomBf, const int* __restrict__ owners,
    const float* __restrict__ w1, const float* __restrict__ b1,
    const float* __restrict__ w2, const float* __restrict__ b2,
    const float* __restrict__ w3, const float* __restrict__ b3,
    float* __restrict__ esum, float* __restrict__ cnt)
{
    int gid  = blockIdx.x * 256 + threadIdx.x;
    int n    = gid >> 6;
    int lane = threadIdx.x & 63;
    float a = bf2f(atomBf[n * 64 + lane]);
    float acc = b1[lane];
    #pragma unroll
    for (int k = 0; k < 64; ++k) acc += __shfl(a, k) * w1[k * 64 + lane];
    float h = silu_(acc);
    acc = b2[lane];
    #pragma unroll
    for (int k = 0; k < 64; ++k) acc += __shfl(h, k) * w2[k * 64 + lane];
    h = silu_(acc);
    float p = h * w3[lane];
    #pragma unroll
    for (int off = 32; off > 0; off >>= 1) p += __shfl_xor(p, off);
    if (lane == 0){
        atomicAdd(&esum[owners[n]], p + b3[0]);
        atomicAdd(&cnt[owners[n]], 1.0f);
    }
}

__global__ void k_final(const float* __restrict__ esum, const float* __restrict__ cnt,
                        float* __restrict__ out){
    int i = threadIdx.x;
    if (i < 128) out[i] = esum[i] / fmaxf(cnt[i], 1.0f);
}

extern "C" void kernel_launch(void* const* d_in, const int* in_sizes, int n_in,
                              void* d_out, int out_size, void* d_ws, size_t ws_size,
                              hipStream_t stream)
{
    (void)in_sizes; (void)n_in; (void)out_size; (void)ws_size;
    const int N_ATOMS = 8192, N_UND = 65536, N_DIR = 131072, N_ANG = 262144;

    const int*   atomic_numbers = (const int*)  d_in[0];
    const float* bb_ag  = (const float*)d_in[1];
    const float* bb_bg  = (const float*)d_in[2];
    const float* ang_b  = (const float*)d_in[3];
    const int*   agraph = (const int*)  d_in[4];
    const int*   d2u    = (const int*)  d_in[5];
    const int*   bga    = (const int*)  d_in[6];
    const int*   bgb    = (const int*)  d_in[7];
    const int*   owners = (const int*)  d_in[8];
    const float* emb    = (const float*)d_in[9];
    const float* Wb     = (const float*)d_in[10];
    const float* Wa     = (const float*)d_in[11];
    const float* Wbwag  = (const float*)d_in[12];
    const float* Wbwbg  = (const float*)d_in[13];
    const float* ac_cw1 = (const float*)d_in[14];
    const float* ac_cb1 = (const float*)d_in[15];
    const float* ac_cw2 = (const float*)d_in[16];
    const float* ac_cb2 = (const float*)d_in[17];
    const float* ac_gw1 = (const float*)d_in[18];
    const float* ac_gb1 = (const float*)d_in[19];
    const float* ac_gw2 = (const float*)d_in[20];
    const float* ac_gb2 = (const float*)d_in[21];
    const float* ac_out = (const float*)d_in[22];
    const float* bc_cw1 = (const float*)d_in[23];
    const float* bc_cb1 = (const float*)d_in[24];
    const float* bc_cw2 = (const float*)d_in[25];
    const float* bc_cb2 = (const float*)d_in[26];
    const float* bc_gw1 = (const float*)d_in[27];
    const float* bc_gb1 = (const float*)d_in[28];
    const float* bc_gw2 = (const float*)d_in[29];
    const float* bc_gb2 = (const float*)d_in[30];
    const float* bc_out = (const float*)d_in[31];
    const float* an_cw  = (const float*)d_in[32];
    const float* an_cb  = (const float*)d_in[33];
    const float* an_gw  = (const float*)d_in[34];
    const float* an_gb  = (const float*)d_in[35];
    const float* ro_w1  = (const float*)d_in[36];
    const float* ro_b1  = (const float*)d_in[37];
    const float* ro_w2  = (const float*)d_in[38];
    const float* ro_b2  = (const float*)d_in[39];
    const float* ro_w3  = (const float*)d_in[40];
    const float* ro_b3  = (const float*)d_in[41];

    char* ws = (char*)d_ws;
    size_t off = 0;
    auto alloc = [&](size_t bytes) -> void* {
        void* p = ws + off;
        off = (off + bytes + 255) & ~(size_t)255;
        return p;
    };
    unsigned short* atomBf  = (unsigned short*)alloc((size_t)N_ATOMS * 64 * 2);
    unsigned short* bondBf  = (unsigned short*)alloc((size_t)N_UND   * 64 * 2);
    unsigned short* angleBf = (unsigned short*)alloc((size_t)N_ANG   * 64 * 2);
    unsigned short* bwagBf  = (unsigned short*)alloc((size_t)N_UND   * 64 * 2);
    unsigned short* bwbgBf  = (unsigned short*)alloc((size_t)N_UND   * 64 * 2);
    unsigned short* updBuf  = (unsigned short*)alloc((size_t)N_ANG   * 64 * 2);
    float* esum   = (float*)alloc(128 * 4);
    float* cnt    = (float*)alloc(128 * 4);
    int* offsA = (int*)alloc((N_ATOMS + 1) * 4);
    int* curA  = (int*)alloc(N_ATOMS * 4);
    int* idxA  = (int*)alloc((size_t)N_DIR * 4);
    int* offsB = (int*)alloc((N_UND + 1) * 4);
    int* curB  = (int*)alloc(N_UND * 4);
    int* idxB  = (int*)alloc((size_t)N_ANG * 4);
    unsigned short* acw1cT = (unsigned short*)alloc((size_t)4 * 64 * 192 * 2);
    unsigned short* acw1gT = (unsigned short*)alloc((size_t)4 * 64 * 192 * 2);
    unsigned short* acw2cT = (unsigned short*)alloc((size_t)4 * 64 * 64 * 2);
    unsigned short* acw2gT = (unsigned short*)alloc((size_t)4 * 64 * 64 * 2);
    unsigned short* acoT   = (unsigned short*)alloc((size_t)4 * 64 * 64 * 2);
    unsigned short* bcw1cT = (unsigned short*)alloc((size_t)3 * 64 * 256 * 2);
    unsigned short* bcw1gT = (unsigned short*)alloc((size_t)3 * 64 * 256 * 2);
    unsigned short* bcw2cT = (unsigned short*)alloc((size_t)3 * 64 * 64 * 2);
    unsigned short* bcw2gT = (unsigned short*)alloc((size_t)3 * 64 * 64 * 2);
    unsigned short* bcoT   = (unsigned short*)alloc((size_t)3 * 64 * 64 * 2);
    unsigned short* anwcT  = (unsigned short*)alloc((size_t)3 * 64 * 256 * 2);
    unsigned short* anwgT  = (unsigned short*)alloc((size_t)3 * 64 * 256 * 2);

    auto tc = [&](const float* src, unsigned short* dst, int B, int K){
        int total = B * K * 64;
        k_transconv<<<(total + 255) / 256, 256, 0, stream>>>(src, dst, K, total);
    };
    tc(ac_cw1, acw1cT, 4, 192);  tc(ac_gw1, acw1gT, 4, 192);
    tc(ac_cw2, acw2cT, 4, 64);   tc(ac_gw2, acw2gT, 4, 64);
    tc(ac_out, acoT,   4, 64);
    tc(bc_cw1, bcw1cT, 3, 256);  tc(bc_gw1, bcw1gT, 3, 256);
    tc(bc_cw2, bcw2cT, 3, 64);   tc(bc_gw2, bcw2gT, 3, 64);
    tc(bc_out, bcoT,   3, 64);
    tc(an_cw,  anwcT,  3, 256);  tc(an_gw,  anwgT,  3, 256);

    k_embed<<<N_ATOMS * 64 / 256, 256, 0, stream>>>(emb, atomic_numbers, atomBf);
    k_smallmm<<<N_UND * 64 / 256, 256, 0, stream>>>(bb_ag, Wb,    bondBf);
    k_smallmm<<<N_ANG * 64 / 256, 256, 0, stream>>>(ang_b, Wa,    angleBf);
    k_smallmm<<<N_UND * 64 / 256, 256, 0, stream>>>(bb_ag, Wbwag, bwagBf);
    k_smallmm<<<N_UND * 64 / 256, 256, 0, stream>>>(bb_bg, Wbwbg, bwbgBf);

    // CSR build (graph static across iterations)
    hipMemsetAsync(curA, 0, N_ATOMS * 4, stream);
    k_count<<<(N_DIR + 255) / 256, 256, 0, stream>>>(agraph, 2, N_DIR, curA);
    k_scan<<<1, 1024, 0, stream>>>(curA, offsA, N_ATOMS);
    hipMemsetAsync(curA, 0, N_ATOMS * 4, stream);
    k_fill<<<(N_DIR + 255) / 256, 256, 0, stream>>>(agraph, 2, N_DIR, offsA, curA, idxA);

    hipMemsetAsync(curB, 0, N_UND * 4, stream);
    k_count<<<(N_ANG + 255) / 256, 256, 0, stream>>>(bgb, 2, N_ANG, curB);
    k_scan<<<1, 1024, 0, stream>>>(curB, offsB, N_UND);
    hipMemsetAsync(curB, 0, N_UND * 4, stream);
    k_fill<<<(N_ANG + 255) / 256, 256, 0, stream>>>(bgb, 2, N_ANG, offsB, curB, idxB);

    for (int i = 0; i < 4; ++i){
        k_atom_conv<<<N_DIR / 64, 256, 0, stream>>>(
            atomBf, bondBf, bwagBf, agraph, d2u,
            acw1cT + (size_t)i * 64 * 192, acw1gT + (size_t)i * 64 * 192,
            acw2cT + (size_t)i * 64 * 64,  acw2gT + (size_t)i * 64 * 64,
            acoT   + (size_t)i * 64 * 64,
            ac_cb1 + i * 64, ac_cb2 + i * 64, ac_gb1 + i * 64, ac_gb2 + i * 64, updBuf);
        k_reduce<<<N_ATOMS * 8 / 256, 256, 0, stream>>>(updBuf, offsA, idxA, atomBf, N_ATOMS);
        if (i == 3) break;
        k_bond_conv<<<N_ANG / 64, 256, 0, stream>>>(
            atomBf, bondBf, angleBf, bwbgBf, bga, bgb,
            bcw1cT + (size_t)i * 64 * 256, bcw1gT + (size_t)i * 64 * 256,
            bcw2cT + (size_t)i * 64 * 64,  bcw2gT + (size_t)i * 64 * 64,
            bcoT   + (size_t)i * 64 * 64,
            bc_cb1 + i * 64, bc_cb2 + i * 64, bc_gb1 + i * 64, bc_gb2 + i * 64, updBuf);
        k_reduce<<<N_UND * 8 / 256, 256, 0, stream>>>(updBuf, offsB, idxB, bondBf, N_UND);
        k_angle<<<N_ANG / 64, 256, 0, stream>>>(
            atomBf, bondBf, angleBf, bga, bgb,
            anwcT + (size_t)i * 64 * 256, anwgT + (size_t)i * 64 * 256,
            an_cb + i * 64, an_gb + i * 64);
    }

    hipMemsetAsync(esum, 0, 128 * 4, stream);
    hipMemsetAsync(cnt,  0, 128 * 4, stream);
    k_readout<<<N_ATOMS * 64 / 256, 256, 0, stream>>>(
        atomBf, owners, ro_w1, ro_b1, ro_w2, ro_b2, ro_w3, ro_b3, esum, cnt);
    k_final<<<1, 128, 0, stream>>>(esum, cnt, (float*)d_out);
}

// Round 4
// 913.229 us; speedup vs baseline: 1.4446x; 1.1034x over previous
//
#include <hip/hip_runtime.h>
#include <hip/hip_bf16.h>

typedef float f32x4 __attribute__((ext_vector_type(4)));
typedef short s16x8 __attribute__((ext_vector_type(8)));
typedef unsigned int u32x4 __attribute__((ext_vector_type(4)));

#define DEV static __device__ __forceinline__

DEV unsigned short f2bf(float x){
    unsigned u = __builtin_bit_cast(unsigned, x);
    u += 0x7FFFu + ((u >> 16) & 1u);
    return (unsigned short)(u >> 16);
}
DEV float bf2f(unsigned short h){
    unsigned u = ((unsigned)h) << 16;
    return __builtin_bit_cast(float, u);
}
DEV float sigm_(float x){ return __builtin_amdgcn_rcpf(1.0f + __expf(-x)); }
DEV float silu_(float x){ return x * sigm_(x); }

// ---------------- weight transpose + convert:  src [B][K][64] f32 -> dst [B][64][K] bf16
__global__ __launch_bounds__(256) void k_transconv(const float* __restrict__ src,
                                                   unsigned short* __restrict__ dst,
                                                   int K, int total){
    int gid = blockIdx.x * 256 + threadIdx.x;
    if (gid >= total) return;
    int kn  = K * 64;
    int b   = gid / kn;
    int rem = gid - b * kn;
    int k   = rem >> 6, n = rem & 63;
    dst[b * kn + n * K + k] = f2bf(src[gid]);
}

// ---------------- atom embedding gather
__global__ __launch_bounds__(256) void k_embed(const float* __restrict__ emb,
                                               const int* __restrict__ z,
                                               unsigned short* __restrict__ out){
    int gid = blockIdx.x * 256 + threadIdx.x;
    int n = gid >> 6, f = gid & 63;
    out[gid] = f2bf(emb[z[n] * 64 + f]);
}

// ---------------- bases[rows][9] @ W[9][64] -> bf16 out[rows][64]
__global__ __launch_bounds__(256) void k_smallmm(const float* __restrict__ bases,
                                                 const float* __restrict__ W,
                                                 unsigned short* __restrict__ out){
    int gid = blockIdx.x * 256 + threadIdx.x;
    int r = gid >> 6, f = gid & 63;
    const float* b = bases + r * 9;
    float acc = 0.f;
    #pragma unroll
    for (int k = 0; k < 9; ++k) acc += b[k] * W[k * 64 + f];
    out[gid] = f2bf(acc);
}

// ---------------- CSR build helpers
__global__ void k_count(const int* __restrict__ dst, int stride, int n, int* __restrict__ cnt){
    int i = blockIdx.x * 256 + threadIdx.x;
    if (i < n) atomicAdd(&cnt[dst[(size_t)i * stride]], 1);
}

// hierarchical scan: phase A — per-block (256 counts) sum
__global__ __launch_bounds__(256) void k_bsum(const int* __restrict__ cnt,
                                              int* __restrict__ bsum){
    int i = blockIdx.x * 256 + threadIdx.x;
    int v = cnt[i];
    #pragma unroll
    for (int off = 32; off > 0; off >>= 1) v += __shfl_down(v, off);
    __shared__ int ws[4];
    if ((threadIdx.x & 63) == 0) ws[threadIdx.x >> 6] = v;
    __syncthreads();
    if (threadIdx.x == 0) bsum[blockIdx.x] = ws[0] + ws[1] + ws[2] + ws[3];
}

// phase B — single small block scans the <=256 block sums -> exclusive bases + total
__global__ __launch_bounds__(256) void k_bscan(const int* __restrict__ bsum,
                                               int* __restrict__ bbase, int nb,
                                               int* __restrict__ total_out){
    __shared__ int sh[256];
    int t = threadIdx.x;
    int v = (t < nb) ? bsum[t] : 0;
    sh[t] = v;
    __syncthreads();
    for (int d = 1; d < 256; d <<= 1){
        int u = (t >= d) ? sh[t - d] : 0;
        __syncthreads();
        sh[t] += u;
        __syncthreads();
    }
    if (t < nb) bbase[t] = sh[t] - v;           // exclusive
    if (t == nb - 1) *total_out = sh[t];        // offs[n]
}

// phase C — intra-block exclusive scan + base -> offs[i]
__global__ __launch_bounds__(256) void k_offs(const int* __restrict__ cnt,
                                              const int* __restrict__ bbase,
                                              int* __restrict__ offs){
    __shared__ int sh[256];
    int t = threadIdx.x;
    int i = blockIdx.x * 256 + t;
    int v = cnt[i];
    sh[t] = v;
    __syncthreads();
    for (int d = 1; d < 256; d <<= 1){
        int u = (t >= d) ? sh[t - d] : 0;
        __syncthreads();
        sh[t] += u;
        __syncthreads();
    }
    offs[i] = bbase[blockIdx.x] + sh[t] - v;
}

__global__ void k_fill(const int* __restrict__ dst, int stride, int n,
                       const int* __restrict__ offs, int* __restrict__ cur,
                       int* __restrict__ idx){
    int i = blockIdx.x * 256 + threadIdx.x;
    if (i < n){
        int d = dst[(size_t)i * stride];
        int p = offs[d] + atomicAdd(&cur[d], 1);
        idx[p] = i;
    }
}

// ---------------- gather-reduce: act[row] += sum_{j in bucket(row)} upd[idx[j]]
__global__ __launch_bounds__(256) void k_reduce(const unsigned short* __restrict__ upd,
                                                const int* __restrict__ offs,
                                                const int* __restrict__ idx,
                                                unsigned short* __restrict__ act, int nRows){
    int gid = blockIdx.x * 256 + threadIdx.x;
    int row = gid >> 3;
    if (row >= nRows) return;
    int c8 = (gid & 7) * 8;
    int o = offs[row], e = offs[row + 1];
    float acc[8] = {};
    for (int j = o; j < e; ++j){
        s16x8 v = *(const s16x8*)&upd[(size_t)idx[j] * 64 + c8];
        #pragma unroll
        for (int q = 0; q < 8; ++q) acc[q] += bf2f((unsigned short)v[q]);
    }
    s16x8 a = *(s16x8*)&act[(size_t)row * 64 + c8];
    #pragma unroll
    for (int q = 0; q < 8; ++q) a[q] = (short)f2bf(bf2f((unsigned short)a[q]) + acc[q]);
    *(s16x8*)&act[(size_t)row * 64 + c8] = a;
}

#define MFMA16(a,b,c) __builtin_amdgcn_mfma_f32_16x16x32_bf16(a,b,c,0,0,0)

// ---------------- atom conv: gathered gmlp over edges, W_out pre-applied, dense upd write
__global__ __launch_bounds__(256, 4) void k_atom_conv(
    const unsigned short* __restrict__ atomBf, const unsigned short* __restrict__ bondBf,
    const unsigned short* __restrict__ bwagBf,
    const int* __restrict__ agraph, const int* __restrict__ d2u,
    const unsigned short* __restrict__ w1cT, const unsigned short* __restrict__ w1gT,
    const unsigned short* __restrict__ w2cT, const unsigned short* __restrict__ w2gT,
    const unsigned short* __restrict__ woT,
    const float* __restrict__ cb1, const float* __restrict__ cb2,
    const float* __restrict__ gb1, const float* __restrict__ gb2,
    unsigned short* __restrict__ upd)
{
    __shared__ unsigned short lds[14208];   // overlay: ldsA [64][200] | HC,HG,V [64][74]
    __shared__ int ldsIdx[64];
    unsigned short* ldsA  = lds;
    unsigned short* ldsHC = lds;
    unsigned short* ldsHG = lds + 4736;
    unsigned short* ldsV  = lds + 9472;
    const int tid = threadIdx.x;
    const int r0  = blockIdx.x * 64;

    {   // stage: thread (srow, q) copies one 128B source row
        const int srow = tid >> 2, q = tid & 3;
        int e = r0 + srow;
        if (q < 3){
            const unsigned short* src;
            if (q == 0)      src = atomBf + (size_t)agraph[2 * e] * 64;
            else if (q == 1){ int u = d2u[e]; ldsIdx[srow] = u; src = bondBf + (size_t)u * 64; }
            else             src = atomBf + (size_t)agraph[2 * e + 1] * 64;
            #pragma unroll
            for (int j = 0; j < 8; ++j)
                *(u32x4*)&ldsA[srow * 200 + q * 64 + j * 8] = *(const u32x4*)(src + j * 8);
        }
    }
    __syncthreads();

    const int lane = tid & 63;
    const int r16  = lane & 15;
    const int grp  = lane >> 4;
    const int col  = (tid >> 6) * 16 + r16;

    // issue bw gather early; consumed only in the epilogue
    unsigned short bwv[16];
    #pragma unroll
    for (int mt = 0; mt < 4; ++mt)
        #pragma unroll
        for (int j = 0; j < 4; ++j)
            bwv[mt * 4 + j] = bwagBf[(size_t)ldsIdx[mt * 16 + grp * 4 + j] * 64 + col];

    f32x4 aC[4] = {}, aG[4] = {};
    #pragma unroll
    for (int kt = 0; kt < 6; ++kt){
        s16x8 bc = *(const s16x8*)&w1cT[col * 192 + kt * 32 + grp * 8];
        s16x8 bg = *(const s16x8*)&w1gT[col * 192 + kt * 32 + grp * 8];
        #pragma unroll
        for (int mt = 0; mt < 4; ++mt){
            s16x8 a = *(const s16x8*)&ldsA[(mt * 16 + r16) * 200 + kt * 32 + grp * 8];
            aC[mt] = MFMA16(a, bc, aC[mt]);
            aG[mt] = MFMA16(a, bg, aG[mt]);
        }
    }
    __syncthreads();   // ldsA dead; overlay writable

    const float bC1 = cb1[col], bG1 = gb1[col];
    #pragma unroll
    for (int mt = 0; mt < 4; ++mt){
        #pragma unroll
        for (int j = 0; j < 4; ++j){
            int row = mt * 16 + grp * 4 + j;
            ldsHC[row * 74 + col] = f2bf(silu_(aC[mt][j] + bC1));
            ldsHG[row * 74 + col] = f2bf(silu_(aG[mt][j] + bG1));
        }
    }
    __syncthreads();

    f32x4 oC[4] = {}, oG[4] = {};
    #pragma unroll
    for (int kt = 0; kt < 2; ++kt){
        s16x8 bc = *(const s16x8*)&w2cT[col * 64 + kt * 32 + grp * 8];
        s16x8 bg = *(const s16x8*)&w2gT[col * 64 + kt * 32 + grp * 8];
        #pragma unroll
        for (int mt = 0; mt < 4; ++mt){
            s16x8 hc = *(const s16x8*)&ldsHC[(mt * 16 + r16) * 74 + kt * 32 + grp * 8];
            s16x8 hg = *(const s16x8*)&ldsHG[(mt * 16 + r16) * 74 + kt * 32 + grp * 8];
            oC[mt] = MFMA16(hc, bc, oC[mt]);
            oG[mt] = MFMA16(hg, bg, oG[mt]);
        }
    }
    const float bC2 = cb2[col], bG2 = gb2[col];
    #pragma unroll
    for (int mt = 0; mt < 4; ++mt){
        #pragma unroll
        for (int j = 0; j < 4; ++j){
            int row = mt * 16 + grp * 4 + j;
            float v = silu_(oC[mt][j] + bC2) * sigm_(oG[mt][j] + bG2);
            v *= bf2f(bwv[mt * 4 + j]);
            ldsV[row * 74 + col] = f2bf(v);
        }
    }
    __syncthreads();

    f32x4 oD[4] = {};
    #pragma unroll
    for (int kt = 0; kt < 2; ++kt){
        s16x8 bo = *(const s16x8*)&woT[col * 64 + kt * 32 + grp * 8];
        #pragma unroll
        for (int mt = 0; mt < 4; ++mt){
            s16x8 a = *(const s16x8*)&ldsV[(mt * 16 + r16) * 74 + kt * 32 + grp * 8];
            oD[mt] = MFMA16(a, bo, oD[mt]);
        }
    }
    #pragma unroll
    for (int mt = 0; mt < 4; ++mt){
        #pragma unroll
        for (int j = 0; j < 4; ++j){
            int row = mt * 16 + grp * 4 + j;
            upd[(size_t)(r0 + row) * 64 + col] = f2bf(oD[mt][j]);
        }
    }
}

// ---------------- bond conv: gathered gmlp over angles, W_out pre-applied, dense upd write
__global__ __launch_bounds__(256, 4) void k_bond_conv(
    const unsigned short* __restrict__ atomBf, const unsigned short* __restrict__ bondBf,
    const unsigned short* __restrict__ angleBf, const unsigned short* __restrict__ bwbgBf,
    const int* __restrict__ bga, const int* __restrict__ bgb,
    const unsigned short* __restrict__ w1cT, const unsigned short* __restrict__ w1gT,
    const unsigned short* __restrict__ w2cT, const unsigned short* __restrict__ w2gT,
    const unsigned short* __restrict__ woT,
    const float* __restrict__ cb1, const float* __restrict__ cb2,
    const float* __restrict__ gb1, const float* __restrict__ gb2,
    unsigned short* __restrict__ upd)
{
    __shared__ unsigned short lds[16896];   // overlay: ldsA [64][264] | HC,HG,V [64][74]
    __shared__ int ldsIdx[64];
    unsigned short* ldsA  = lds;
    unsigned short* ldsHC = lds;
    unsigned short* ldsHG = lds + 4736;
    unsigned short* ldsV  = lds + 9472;
    const int tid = threadIdx.x;
    const int r0  = blockIdx.x * 64;

    {
        const int srow = tid >> 2, q = tid & 3;
        int a = r0 + srow;
        const unsigned short* src;
        if (q == 0){ int2 bb = *(const int2*)&bgb[2 * a]; ldsIdx[srow] = bb.x;
                     src = bondBf + (size_t)bb.x * 64; }
        else if (q == 1){ src = bondBf  + (size_t)bgb[2 * a + 1] * 64; }
        else if (q == 2){ src = angleBf + (size_t)a * 64; }
        else            { src = atomBf  + (size_t)bga[a] * 64; }
        #pragma unroll
        for (int j = 0; j < 8; ++j)
            *(u32x4*)&ldsA[srow * 264 + q * 64 + j * 8] = *(const u32x4*)(src + j * 8);
    }
    __syncthreads();

    const int lane = tid & 63;
    const int r16  = lane & 15;
    const int grp  = lane >> 4;
    const int col  = (tid >> 6) * 16 + r16;

    unsigned short bwv[16];
    #pragma unroll
    for (int mt = 0; mt < 4; ++mt)
        #pragma unroll
        for (int j = 0; j < 4; ++j)
            bwv[mt * 4 + j] = bwbgBf[(size_t)ldsIdx[mt * 16 + grp * 4 + j] * 64 + col];

    f32x4 aC[4] = {}, aG[4] = {};
    #pragma unroll
    for (int kt = 0; kt < 8; ++kt){
        s16x8 bc = *(const s16x8*)&w1cT[col * 256 + kt * 32 + grp * 8];
        s16x8 bg = *(const s16x8*)&w1gT[col * 256 + kt * 32 + grp * 8];
        #pragma unroll
        for (int mt = 0; mt < 4; ++mt){
            s16x8 a = *(const s16x8*)&ldsA[(mt * 16 + r16) * 264 + kt * 32 + grp * 8];
            aC[mt] = MFMA16(a, bc, aC[mt]);
            aG[mt] = MFMA16(a, bg, aG[mt]);
        }
    }
    __syncthreads();

    const float bC1 = cb1[col], bG1 = gb1[col];
    #pragma unroll
    for (int mt = 0; mt < 4; ++mt){
        #pragma unroll
        for (int j = 0; j < 4; ++j){
            int row = mt * 16 + grp * 4 + j;
            ldsHC[row * 74 + col] = f2bf(silu_(aC[mt][j] + bC1));
            ldsHG[row * 74 + col] = f2bf(silu_(aG[mt][j] + bG1));
        }
    }
    __syncthreads();

    f32x4 oC[4] = {}, oG[4] = {};
    #pragma unroll
    for (int kt = 0; kt < 2; ++kt){
        s16x8 bc = *(const s16x8*)&w2cT[col * 64 + kt * 32 + grp * 8];
        s16x8 bg = *(const s16x8*)&w2gT[col * 64 + kt * 32 + grp * 8];
        #pragma unroll
        for (int mt = 0; mt < 4; ++mt){
            s16x8 hc = *(const s16x8*)&ldsHC[(mt * 16 + r16) * 74 + kt * 32 + grp * 8];
            s16x8 hg = *(const s16x8*)&ldsHG[(mt * 16 + r16) * 74 + kt * 32 + grp * 8];
            oC[mt] = MFMA16(hc, bc, oC[mt]);
            oG[mt] = MFMA16(hg, bg, oG[mt]);
        }
    }
    const float bC2 = cb2[col], bG2 = gb2[col];
    #pragma unroll
    for (int mt = 0; mt < 4; ++mt){
        #pragma unroll
        for (int j = 0; j < 4; ++j){
            int row = mt * 16 + grp * 4 + j;
            float v = silu_(oC[mt][j] + bC2) * sigm_(oG[mt][j] + bG2);
            v *= bf2f(bwv[mt * 4 + j]);
            ldsV[row * 74 + col] = f2bf(v);
        }
    }
    __syncthreads();

    f32x4 oD[4] = {};
    #pragma unroll
    for (int kt = 0; kt < 2; ++kt){
        s16x8 bo = *(const s16x8*)&woT[col * 64 + kt * 32 + grp * 8];
        #pragma unroll
        for (int mt = 0; mt < 4; ++mt){
            s16x8 a = *(const s16x8*)&ldsV[(mt * 16 + r16) * 74 + kt * 32 + grp * 8];
            oD[mt] = MFMA16(a, bo, oD[mt]);
        }
    }
    #pragma unroll
    for (int mt = 0; mt < 4; ++mt){
        #pragma unroll
        for (int j = 0; j < 4; ++j){
            int row = mt * 16 + grp * 4 + j;
            upd[(size_t)(r0 + row) * 64 + col] = f2bf(oD[mt][j]);
        }
    }
}

// ---------------- angle update (single gated layer), in-place residual on angleBf
__global__ __launch_bounds__(256, 4) void k_angle(
    const unsigned short* __restrict__ atomBf, const unsigned short* __restrict__ bondBf,
    unsigned short* __restrict__ angleBf,
    const int* __restrict__ bga, const int* __restrict__ bgb,
    const unsigned short* __restrict__ wcT, const unsigned short* __restrict__ wgT,
    const float* __restrict__ cb, const float* __restrict__ gb)
{
    __shared__ unsigned short ldsA[64 * 264];
    const int tid = threadIdx.x;
    const int r0  = blockIdx.x * 64;

    {
        const int srow = tid >> 2, q = tid & 3;
        int a = r0 + srow;
        const unsigned short* src;
        if (q == 0)      src = bondBf  + (size_t)bgb[2 * a] * 64;
        else if (q == 1) src = bondBf  + (size_t)bgb[2 * a + 1] * 64;
        else if (q == 2) src = angleBf + (size_t)a * 64;
        else             src = atomBf  + (size_t)bga[a] * 64;
        #pragma unroll
        for (int j = 0; j < 8; ++j)
            *(u32x4*)&ldsA[srow * 264 + q * 64 + j * 8] = *(const u32x4*)(src + j * 8);
    }
    __syncthreads();

    const int lane = tid & 63;
    const int r16  = lane & 15;
    const int grp  = lane >> 4;
    const int col  = (tid >> 6) * 16 + r16;

    f32x4 aC[4] = {}, aG[4] = {};
    #pragma unroll
    for (int kt = 0; kt < 8; ++kt){
        s16x8 bc = *(const s16x8*)&wcT[col * 256 + kt * 32 + grp * 8];
        s16x8 bg = *(const s16x8*)&wgT[col * 256 + kt * 32 + grp * 8];
        #pragma unroll
        for (int mt = 0; mt < 4; ++mt){
            s16x8 a = *(const s16x8*)&ldsA[(mt * 16 + r16) * 264 + kt * 32 + grp * 8];
            aC[mt] = MFMA16(a, bc, aC[mt]);
            aG[mt] = MFMA16(a, bg, aG[mt]);
        }
    }
    const float bC = cb[col], bG = gb[col];
    #pragma unroll
    for (int mt = 0; mt < 4; ++mt){
        #pragma unroll
        for (int j = 0; j < 4; ++j){
            int row = mt * 16 + grp * 4 + j;
            int a = r0 + row;
            float oldv = bf2f(ldsA[row * 264 + 128 + col]);
            float v = silu_(aC[mt][j] + bC) * sigm_(aG[mt][j] + bG);
            angleBf[(size_t)a * 64 + col] = f2bf(oldv + v);
        }
    }
}

// ---------------- readout MLP + segmented sum (wave per atom row)
__global__ __launch_bounds__(256) void k_readout(
    const unsigned short* __restrict__ atomBf, const int* __restrict__ owners,
    const float* __restrict__ w1, const float* __restrict__ b1,
    const float* __restrict__ w2, const float* __restrict__ b2,
    const float* __restrict__ w3, const float* __restrict__ b3,
    float* __restrict__ esum, float* __restrict__ cnt)
{
    int gid  = blockIdx.x * 256 + threadIdx.x;
    int n    = gid >> 6;
    int lane = threadIdx.x & 63;
    float a = bf2f(atomBf[n * 64 + lane]);
    float acc = b1[lane];
    #pragma unroll
    for (int k = 0; k < 64; ++k) acc += __shfl(a, k) * w1[k * 64 + lane];
    float h = silu_(acc);
    acc = b2[lane];
    #pragma unroll
    for (int k = 0; k < 64; ++k) acc += __shfl(h, k) * w2[k * 64 + lane];
    h = silu_(acc);
    float p = h * w3[lane];
    #pragma unroll
    for (int off = 32; off > 0; off >>= 1) p += __shfl_xor(p, off);
    if (lane == 0){
        atomicAdd(&esum[owners[n]], p + b3[0]);
        atomicAdd(&cnt[owners[n]], 1.0f);
    }
}

__global__ void k_final(const float* __restrict__ esum, const float* __restrict__ cnt,
                        float* __restrict__ out){
    int i = threadIdx.x;
    if (i < 128) out[i] = esum[i] / fmaxf(cnt[i], 1.0f);
}

extern "C" void kernel_launch(void* const* d_in, const int* in_sizes, int n_in,
                              void* d_out, int out_size, void* d_ws, size_t ws_size,
                              hipStream_t stream)
{
    (void)in_sizes; (void)n_in; (void)out_size; (void)ws_size;
    const int N_ATOMS = 8192, N_UND = 65536, N_DIR = 131072, N_ANG = 262144;

    const int*   atomic_numbers = (const int*)  d_in[0];
    const float* bb_ag  = (const float*)d_in[1];
    const float* bb_bg  = (const float*)d_in[2];
    const float* ang_b  = (const float*)d_in[3];
    const int*   agraph = (const int*)  d_in[4];
    const int*   d2u    = (const int*)  d_in[5];
    const int*   bga    = (const int*)  d_in[6];
    const int*   bgb    = (const int*)  d_in[7];
    const int*   owners = (const int*)  d_in[8];
    const float* emb    = (const float*)d_in[9];
    const float* Wb     = (const float*)d_in[10];
    const float* Wa     = (const float*)d_in[11];
    const float* Wbwag  = (const float*)d_in[12];
    const float* Wbwbg  = (const float*)d_in[13];
    const float* ac_cw1 = (const float*)d_in[14];
    const float* ac_cb1 = (const float*)d_in[15];
    const float* ac_cw2 = (const float*)d_in[16];
    const float* ac_cb2 = (const float*)d_in[17];
    const float* ac_gw1 = (const float*)d_in[18];
    const float* ac_gb1 = (const float*)d_in[19];
    const float* ac_gw2 = (const float*)d_in[20];
    const float* ac_gb2 = (const float*)d_in[21];
    const float* ac_out = (const float*)d_in[22];
    const float* bc_cw1 = (const float*)d_in[23];
    const float* bc_cb1 = (const float*)d_in[24];
    const float* bc_cw2 = (const float*)d_in[25];
    const float* bc_cb2 = (const float*)d_in[26];
    const float* bc_gw1 = (const float*)d_in[27];
    const float* bc_gb1 = (const float*)d_in[28];
    const float* bc_gw2 = (const float*)d_in[29];
    const float* bc_gb2 = (const float*)d_in[30];
    const float* bc_out = (const float*)d_in[31];
    const float* an_cw  = (const float*)d_in[32];
    const float* an_cb  = (const float*)d_in[33];
    const float* an_gw  = (const float*)d_in[34];
    const float* an_gb  = (const float*)d_in[35];
    const float* ro_w1  = (const float*)d_in[36];
    const float* ro_b1  = (const float*)d_in[37];
    const float* ro_w2  = (const float*)d_in[38];
    const float* ro_b2  = (const float*)d_in[39];
    const float* ro_w3  = (const float*)d_in[40];
    const float* ro_b3  = (const float*)d_in[41];

    char* ws = (char*)d_ws;
    size_t off = 0;
    auto alloc = [&](size_t bytes) -> void* {
        void* p = ws + off;
        off = (off + bytes + 255) & ~(size_t)255;
        return p;
    };
    unsigned short* atomBf  = (unsigned short*)alloc((size_t)N_ATOMS * 64 * 2);
    unsigned short* bondBf  = (unsigned short*)alloc((size_t)N_UND   * 64 * 2);
    unsigned short* angleBf = (unsigned short*)alloc((size_t)N_ANG   * 64 * 2);
    unsigned short* bwagBf  = (unsigned short*)alloc((size_t)N_UND   * 64 * 2);
    unsigned short* bwbgBf  = (unsigned short*)alloc((size_t)N_UND   * 64 * 2);
    unsigned short* updBuf  = (unsigned short*)alloc((size_t)N_ANG   * 64 * 2);
    float* esum   = (float*)alloc(128 * 4);
    float* cnt    = (float*)alloc(128 * 4);
    int* offsA = (int*)alloc((N_ATOMS + 1) * 4);
    int* curA  = (int*)alloc(N_ATOMS * 4);
    int* idxA  = (int*)alloc((size_t)N_DIR * 4);
    int* offsB = (int*)alloc((N_UND + 1) * 4);
    int* curB  = (int*)alloc(N_UND * 4);
    int* idxB  = (int*)alloc((size_t)N_ANG * 4);
    int* bsum  = (int*)alloc(256 * 4);
    int* bbase = (int*)alloc(256 * 4);
    unsigned short* acw1cT = (unsigned short*)alloc((size_t)4 * 64 * 192 * 2);
    unsigned short* acw1gT = (unsigned short*)alloc((size_t)4 * 64 * 192 * 2);
    unsigned short* acw2cT = (unsigned short*)alloc((size_t)4 * 64 * 64 * 2);
    unsigned short* acw2gT = (unsigned short*)alloc((size_t)4 * 64 * 64 * 2);
    unsigned short* acoT   = (unsigned short*)alloc((size_t)4 * 64 * 64 * 2);
    unsigned short* bcw1cT = (unsigned short*)alloc((size_t)3 * 64 * 256 * 2);
    unsigned short* bcw1gT = (unsigned short*)alloc((size_t)3 * 64 * 256 * 2);
    unsigned short* bcw2cT = (unsigned short*)alloc((size_t)3 * 64 * 64 * 2);
    unsigned short* bcw2gT = (unsigned short*)alloc((size_t)3 * 64 * 64 * 2);
    unsigned short* bcoT   = (unsigned short*)alloc((size_t)3 * 64 * 64 * 2);
    unsigned short* anwcT  = (unsigned short*)alloc((size_t)3 * 64 * 256 * 2);
    unsigned short* anwgT  = (unsigned short*)alloc((size_t)3 * 64 * 256 * 2);

    auto tc = [&](const float* src, unsigned short* dst, int B, int K){
        int total = B * K * 64;
        k_transconv<<<(total + 255) / 256, 256, 0, stream>>>(src, dst, K, total);
    };
    tc(ac_cw1, acw1cT, 4, 192);  tc(ac_gw1, acw1gT, 4, 192);
    tc(ac_cw2, acw2cT, 4, 64);   tc(ac_gw2, acw2gT, 4, 64);
    tc(ac_out, acoT,   4, 64);
    tc(bc_cw1, bcw1cT, 3, 256);  tc(bc_gw1, bcw1gT, 3, 256);
    tc(bc_cw2, bcw2cT, 3, 64);   tc(bc_gw2, bcw2gT, 3, 64);
    tc(bc_out, bcoT,   3, 64);
    tc(an_cw,  anwcT,  3, 256);  tc(an_gw,  anwgT,  3, 256);

    k_embed<<<N_ATOMS * 64 / 256, 256, 0, stream>>>(emb, atomic_numbers, atomBf);
    k_smallmm<<<N_UND * 64 / 256, 256, 0, stream>>>(bb_ag, Wb,    bondBf);
    k_smallmm<<<N_ANG * 64 / 256, 256, 0, stream>>>(ang_b, Wa,    angleBf);
    k_smallmm<<<N_UND * 64 / 256, 256, 0, stream>>>(bb_ag, Wbwag, bwagBf);
    k_smallmm<<<N_UND * 64 / 256, 256, 0, stream>>>(bb_bg, Wbwbg, bwbgBf);

    // CSR build (graph static across iterations), hierarchical scan
    hipMemsetAsync(curA, 0, N_ATOMS * 4, stream);
    k_count<<<(N_DIR + 255) / 256, 256, 0, stream>>>(agraph, 2, N_DIR, curA);
    k_bsum <<<N_ATOMS / 256, 256, 0, stream>>>(curA, bsum);
    k_bscan<<<1, 256, 0, stream>>>(bsum, bbase, N_ATOMS / 256, offsA + N_ATOMS);
    k_offs <<<N_ATOMS / 256, 256, 0, stream>>>(curA, bbase, offsA);
    hipMemsetAsync(curA, 0, N_ATOMS * 4, stream);
    k_fill<<<(N_DIR + 255) / 256, 256, 0, stream>>>(agraph, 2, N_DIR, offsA, curA, idxA);

    hipMemsetAsync(curB, 0, N_UND * 4, stream);
    k_count<<<(N_ANG + 255) / 256, 256, 0, stream>>>(bgb, 2, N_ANG, curB);
    k_bsum <<<N_UND / 256, 256, 0, stream>>>(curB, bsum);
    k_bscan<<<1, 256, 0, stream>>>(bsum, bbase, N_UND / 256, offsB + N_UND);
    k_offs <<<N_UND / 256, 256, 0, stream>>>(curB, bbase, offsB);
    hipMemsetAsync(curB, 0, N_UND * 4, stream);
    k_fill<<<(N_ANG + 255) / 256, 256, 0, stream>>>(bgb, 2, N_ANG, offsB, curB, idxB);

    for (int i = 0; i < 4; ++i){
        k_atom_conv<<<N_DIR / 64, 256, 0, stream>>>(
            atomBf, bondBf, bwagBf, agraph, d2u,
            acw1cT + (size_t)i * 64 * 192, acw1gT + (size_t)i * 64 * 192,
            acw2cT + (size_t)i * 64 * 64,  acw2gT + (size_t)i * 64 * 64,
            acoT   + (size_t)i * 64 * 64,
            ac_cb1 + i * 64, ac_cb2 + i * 64, ac_gb1 + i * 64, ac_gb2 + i * 64, updBuf);
        k_reduce<<<N_ATOMS * 8 / 256, 256, 0, stream>>>(updBuf, offsA, idxA, atomBf, N_ATOMS);
        if (i == 3) break;
        k_bond_conv<<<N_ANG / 64, 256, 0, stream>>>(
            atomBf, bondBf, angleBf, bwbgBf, bga, bgb,
            bcw1cT + (size_t)i * 64 * 256, bcw1gT + (size_t)i * 64 * 256,
            bcw2cT + (size_t)i * 64 * 64,  bcw2gT + (size_t)i * 64 * 64,
            bcoT   + (size_t)i * 64 * 64,
            bc_cb1 + i * 64, bc_cb2 + i * 64, bc_gb1 + i * 64, bc_gb2 + i * 64, updBuf);
        k_reduce<<<N_UND * 8 / 256, 256, 0, stream>>>(updBuf, offsB, idxB, bondBf, N_UND);
        k_angle<<<N_ANG / 64, 256, 0, stream>>>(
            atomBf, bondBf, angleBf, bga, bgb,
            anwcT + (size_t)i * 64 * 256, anwgT + (size_t)i * 64 * 256,
            an_cb + i * 64, an_gb + i * 64);
    }

    hipMemsetAsync(esum, 0, 128 * 4, stream);
    hipMemsetAsync(cnt,  0, 128 * 4, stream);
    k_readout<<<N_ATOMS * 64 / 256, 256, 0, stream>>>(
        atomBf, owners, ro_w1, ro_b1, ro_w2, ro_b2, ro_w3, ro_b3, esum, cnt);
    k_final<<<1, 128, 0, stream>>>(esum, cnt, (float*)d_out);
}

// Round 5
// 873.986 us; speedup vs baseline: 1.5095x; 1.0449x over previous
//
#include <hip/hip_runtime.h>
#include <hip/hip_bf16.h>

typedef float f32x4 __attribute__((ext_vector_type(4)));
typedef short s16x8 __attribute__((ext_vector_type(8)));
typedef unsigned int u32x4 __attribute__((ext_vector_type(4)));

#define DEV static __device__ __forceinline__

DEV unsigned short f2bf(float x){
    unsigned u = __builtin_bit_cast(unsigned, x);
    u += 0x7FFFu + ((u >> 16) & 1u);
    return (unsigned short)(u >> 16);
}
DEV float bf2f(unsigned short h){
    unsigned u = ((unsigned)h) << 16;
    return __builtin_bit_cast(float, u);
}
DEV float sigm_(float x){ return __builtin_amdgcn_rcpf(1.0f + __expf(-x)); }
DEV float silu_(float x){ return x * sigm_(x); }

// ---------------- weight transpose + convert:  src [B][K][64] f32 -> dst [B][64][K] bf16
__global__ __launch_bounds__(256) void k_transconv(const float* __restrict__ src,
                                                   unsigned short* __restrict__ dst,
                                                   int K, int total){
    int gid = blockIdx.x * 256 + threadIdx.x;
    if (gid >= total) return;
    int kn  = K * 64;
    int b   = gid / kn;
    int rem = gid - b * kn;
    int k   = rem >> 6, n = rem & 63;
    dst[b * kn + n * K + k] = f2bf(src[gid]);
}

// ---------------- atom embedding gather
__global__ __launch_bounds__(256) void k_embed(const float* __restrict__ emb,
                                               const int* __restrict__ z,
                                               unsigned short* __restrict__ out){
    int gid = blockIdx.x * 256 + threadIdx.x;
    int n = gid >> 6, f = gid & 63;
    out[gid] = f2bf(emb[z[n] * 64 + f]);
}

// ---------------- bases[rows][9] @ W[9][64] -> bf16 out[rows][64]
__global__ __launch_bounds__(256) void k_smallmm(const float* __restrict__ bases,
                                                 const float* __restrict__ W,
                                                 unsigned short* __restrict__ out){
    int gid = blockIdx.x * 256 + threadIdx.x;
    int r = gid >> 6, f = gid & 63;
    const float* b = bases + r * 9;
    float acc = 0.f;
    #pragma unroll
    for (int k = 0; k < 9; ++k) acc += b[k] * W[k * 64 + f];
    out[gid] = f2bf(acc);
}

// ---------------- CSR build helpers
__global__ void k_count(const int* __restrict__ dst, int stride, int n, int* __restrict__ cnt){
    int i = blockIdx.x * 256 + threadIdx.x;
    if (i < n) atomicAdd(&cnt[dst[(size_t)i * stride]], 1);
}

__global__ __launch_bounds__(256) void k_bsum(const int* __restrict__ cnt,
                                              int* __restrict__ bsum){
    int i = blockIdx.x * 256 + threadIdx.x;
    int v = cnt[i];
    #pragma unroll
    for (int off = 32; off > 0; off >>= 1) v += __shfl_down(v, off);
    __shared__ int ws[4];
    if ((threadIdx.x & 63) == 0) ws[threadIdx.x >> 6] = v;
    __syncthreads();
    if (threadIdx.x == 0) bsum[blockIdx.x] = ws[0] + ws[1] + ws[2] + ws[3];
}

__global__ __launch_bounds__(256) void k_bscan(const int* __restrict__ bsum,
                                               int* __restrict__ bbase, int nb,
                                               int* __restrict__ total_out){
    __shared__ int sh[256];
    int t = threadIdx.x;
    int v = (t < nb) ? bsum[t] : 0;
    sh[t] = v;
    __syncthreads();
    for (int d = 1; d < 256; d <<= 1){
        int u = (t >= d) ? sh[t - d] : 0;
        __syncthreads();
        sh[t] += u;
        __syncthreads();
    }
    if (t < nb) bbase[t] = sh[t] - v;
    if (t == nb - 1) *total_out = sh[t];
}

__global__ __launch_bounds__(256) void k_offs(const int* __restrict__ cnt,
                                              const int* __restrict__ bbase,
                                              int* __restrict__ offs){
    __shared__ int sh[256];
    int t = threadIdx.x;
    int i = blockIdx.x * 256 + t;
    int v = cnt[i];
    sh[t] = v;
    __syncthreads();
    for (int d = 1; d < 256; d <<= 1){
        int u = (t >= d) ? sh[t - d] : 0;
        __syncthreads();
        sh[t] += u;
        __syncthreads();
    }
    offs[i] = bbase[blockIdx.x] + sh[t] - v;
}

__global__ void k_fill(const int* __restrict__ dst, int stride, int n,
                       const int* __restrict__ offs, int* __restrict__ cur,
                       int* __restrict__ idx){
    int i = blockIdx.x * 256 + threadIdx.x;
    if (i < n){
        int d = dst[(size_t)i * stride];
        int p = offs[d] + atomicAdd(&cur[d], 1);
        idx[p] = i;
    }
}

// ---------------- gather-reduce (contiguous): act[row] += sum_{j in [offs[row],offs[row+1])} upd[j]
__global__ __launch_bounds__(256) void k_reduce(const unsigned short* __restrict__ upd,
                                                const int* __restrict__ offs,
                                                unsigned short* __restrict__ act, int nRows){
    int gid = blockIdx.x * 256 + threadIdx.x;
    int row = gid >> 3;
    if (row >= nRows) return;
    int c8 = (gid & 7) * 8;
    int o = offs[row], e = offs[row + 1];
    float acc[8] = {};
    for (int j = o; j < e; ++j){
        s16x8 v = *(const s16x8*)&upd[(size_t)j * 64 + c8];
        #pragma unroll
        for (int q = 0; q < 8; ++q) acc[q] += bf2f((unsigned short)v[q]);
    }
    s16x8 a = *(s16x8*)&act[(size_t)row * 64 + c8];
    #pragma unroll
    for (int q = 0; q < 8; ++q) a[q] = (short)f2bf(bf2f((unsigned short)a[q]) + acc[q]);
    *(s16x8*)&act[(size_t)row * 64 + c8] = a;
}

#define MFMA16(a,b,c) __builtin_amdgcn_mfma_f32_16x16x32_bf16(a,b,c,0,0,0)

// ---------------- atom conv: edges processed in CSR-sorted order (by center atom)
__global__ __launch_bounds__(256, 4) void k_atom_conv(
    const unsigned short* __restrict__ atomBf, const unsigned short* __restrict__ bondBf,
    const unsigned short* __restrict__ bwagBf,
    const int* __restrict__ agraph, const int* __restrict__ d2u,
    const int* __restrict__ idxA,
    const unsigned short* __restrict__ w1cT, const unsigned short* __restrict__ w1gT,
    const unsigned short* __restrict__ w2cT, const unsigned short* __restrict__ w2gT,
    const unsigned short* __restrict__ woT,
    const float* __restrict__ cb1, const float* __restrict__ cb2,
    const float* __restrict__ gb1, const float* __restrict__ gb2,
    unsigned short* __restrict__ upd)
{
    __shared__ unsigned short lds[14208];   // overlay: ldsA [64][200] | HC,HG,V [64][74]
    __shared__ unsigned short ldsBw[64 * 68];
    __shared__ int ldsSrc[256];
    unsigned short* ldsA  = lds;
    unsigned short* ldsHC = lds;
    unsigned short* ldsHG = lds + 4736;
    unsigned short* ldsV  = lds + 9472;
    const int tid = threadIdx.x;
    const int r0  = blockIdx.x * 64;

    {   // phase 0: source row indices. q blocks: 0=atom[ag0] 1=bond[d2u] 2=atom[ag1] 3=bw[d2u]
        int q = tid >> 6, row = tid & 63;
        int e = idxA[r0 + row];
        int s;
        if (q == 0)      s = agraph[2 * e];
        else if (q == 1) s = d2u[e];
        else if (q == 2) s = agraph[2 * e + 1];
        else             s = d2u[e];
        ldsSrc[tid] = s;
    }
    __syncthreads();
    {   // phase 1: coalesced copies, 8 lanes per 128B row
        const int lane8 = tid & 7;
        #pragma unroll
        for (int p = 0; p < 8; ++p){
            int cc = p * 32 + (tid >> 3);
            int q = cc >> 6, row = cc & 63;
            int s = ldsSrc[cc];
            const unsigned short* buf = (q == 1 || q == 3) ? bondBf : atomBf;
            if (q == 3) buf = bwagBf;
            u32x4 v = *(const u32x4*)(buf + (size_t)s * 64 + lane8 * 8);
            if (q < 3) *(u32x4*)&ldsA[row * 200 + q * 64 + lane8 * 8] = v;
            else       *(u32x4*)&ldsBw[row * 68 + lane8 * 8] = v;
        }
    }
    __syncthreads();

    const int lane = tid & 63;
    const int r16  = lane & 15;
    const int grp  = lane >> 4;
    const int col  = (tid >> 6) * 16 + r16;

    f32x4 aC[4] = {}, aG[4] = {};
    #pragma unroll
    for (int kt = 0; kt < 6; ++kt){
        s16x8 bc = *(const s16x8*)&w1cT[col * 192 + kt * 32 + grp * 8];
        s16x8 bg = *(const s16x8*)&w1gT[col * 192 + kt * 32 + grp * 8];
        #pragma unroll
        for (int mt = 0; mt < 4; ++mt){
            s16x8 a = *(const s16x8*)&ldsA[(mt * 16 + r16) * 200 + kt * 32 + grp * 8];
            aC[mt] = MFMA16(a, bc, aC[mt]);
            aG[mt] = MFMA16(a, bg, aG[mt]);
        }
    }
    __syncthreads();   // ldsA dead; overlay writable

    const float bC1 = cb1[col], bG1 = gb1[col];
    #pragma unroll
    for (int mt = 0; mt < 4; ++mt){
        #pragma unroll
        for (int j = 0; j < 4; ++j){
            int row = mt * 16 + grp * 4 + j;
            ldsHC[row * 74 + col] = f2bf(silu_(aC[mt][j] + bC1));
            ldsHG[row * 74 + col] = f2bf(silu_(aG[mt][j] + bG1));
        }
    }
    __syncthreads();

    f32x4 oC[4] = {}, oG[4] = {};
    #pragma unroll
    for (int kt = 0; kt < 2; ++kt){
        s16x8 bc = *(const s16x8*)&w2cT[col * 64 + kt * 32 + grp * 8];
        s16x8 bg = *(const s16x8*)&w2gT[col * 64 + kt * 32 + grp * 8];
        #pragma unroll
        for (int mt = 0; mt < 4; ++mt){
            s16x8 hc = *(const s16x8*)&ldsHC[(mt * 16 + r16) * 74 + kt * 32 + grp * 8];
            s16x8 hg = *(const s16x8*)&ldsHG[(mt * 16 + r16) * 74 + kt * 32 + grp * 8];
            oC[mt] = MFMA16(hc, bc, oC[mt]);
            oG[mt] = MFMA16(hg, bg, oG[mt]);
        }
    }
    const float bC2 = cb2[col], bG2 = gb2[col];
    #pragma unroll
    for (int mt = 0; mt < 4; ++mt){
        #pragma unroll
        for (int j = 0; j < 4; ++j){
            int row = mt * 16 + grp * 4 + j;
            float v = silu_(oC[mt][j] + bC2) * sigm_(oG[mt][j] + bG2);
            v *= bf2f(ldsBw[row * 68 + col]);
            ldsV[row * 74 + col] = f2bf(v);
        }
    }
    __syncthreads();

    f32x4 oD[4] = {};
    #pragma unroll
    for (int kt = 0; kt < 2; ++kt){
        s16x8 bo = *(const s16x8*)&woT[col * 64 + kt * 32 + grp * 8];
        #pragma unroll
        for (int mt = 0; mt < 4; ++mt){
            s16x8 a = *(const s16x8*)&ldsV[(mt * 16 + r16) * 74 + kt * 32 + grp * 8];
            oD[mt] = MFMA16(a, bo, oD[mt]);
        }
    }
    #pragma unroll
    for (int mt = 0; mt < 4; ++mt){
        #pragma unroll
        for (int j = 0; j < 4; ++j){
            int row = mt * 16 + grp * 4 + j;
            upd[(size_t)(r0 + row) * 64 + col] = f2bf(oD[mt][j]);   // dense in sorted space
        }
    }
}

// ---------------- bond conv: angles processed in CSR-sorted order (by bgi)
__global__ __launch_bounds__(256, 4) void k_bond_conv(
    const unsigned short* __restrict__ atomBf, const unsigned short* __restrict__ bondBf,
    const unsigned short* __restrict__ angleBf, const unsigned short* __restrict__ bwbgBf,
    const int* __restrict__ bga, const int* __restrict__ bgb,
    const int* __restrict__ idxB,
    const unsigned short* __restrict__ w1cT, const unsigned short* __restrict__ w1gT,
    const unsigned short* __restrict__ w2cT, const unsigned short* __restrict__ w2gT,
    const unsigned short* __restrict__ woT,
    const float* __restrict__ cb1, const float* __restrict__ cb2,
    const float* __restrict__ gb1, const float* __restrict__ gb2,
    unsigned short* __restrict__ upd)
{
    __shared__ unsigned short lds[16896];   // overlay: ldsA [64][264] | HC,HG,V [64][74]
    __shared__ int ldsSrc[256];
    unsigned short* ldsA  = lds;
    unsigned short* ldsHC = lds;
    unsigned short* ldsHG = lds + 4736;
    unsigned short* ldsV  = lds + 9472;
    const int tid = threadIdx.x;
    const int r0  = blockIdx.x * 64;

    {   // q blocks: 0=bond[bgi] 1=bond[bgj] 2=angle 3=atom[bga]
        int q = tid >> 6, row = tid & 63;
        int a = idxB[r0 + row];
        int s;
        if (q == 0)      s = bgb[2 * a];
        else if (q == 1) s = bgb[2 * a + 1];
        else if (q == 2) s = a;
        else             s = bga[a];
        ldsSrc[tid] = s;
    }
    __syncthreads();
    {
        const int lane8 = tid & 7;
        #pragma unroll
        for (int p = 0; p < 8; ++p){
            int cc = p * 32 + (tid >> 3);
            int q = cc >> 6, row = cc & 63;
            int s = ldsSrc[cc];
            const unsigned short* buf = (q < 2) ? bondBf : (q == 2 ? angleBf : atomBf);
            u32x4 v = *(const u32x4*)(buf + (size_t)s * 64 + lane8 * 8);
            *(u32x4*)&ldsA[row * 264 + q * 64 + lane8 * 8] = v;
        }
    }
    __syncthreads();

    const int lane = tid & 63;
    const int r16  = lane & 15;
    const int grp  = lane >> 4;
    const int col  = (tid >> 6) * 16 + r16;

    // bw gather (bgi rows, sorted -> cache-friendly), issued early
    unsigned short bwv[16];
    #pragma unroll
    for (int mt = 0; mt < 4; ++mt)
        #pragma unroll
        for (int j = 0; j < 4; ++j)
            bwv[mt * 4 + j] = bwbgBf[(size_t)ldsSrc[mt * 16 + grp * 4 + j] * 64 + col];

    f32x4 aC[4] = {}, aG[4] = {};
    #pragma unroll
    for (int kt = 0; kt < 8; ++kt){
        s16x8 bc = *(const s16x8*)&w1cT[col * 256 + kt * 32 + grp * 8];
        s16x8 bg = *(const s16x8*)&w1gT[col * 256 + kt * 32 + grp * 8];
        #pragma unroll
        for (int mt = 0; mt < 4; ++mt){
            s16x8 a = *(const s16x8*)&ldsA[(mt * 16 + r16) * 264 + kt * 32 + grp * 8];
            aC[mt] = MFMA16(a, bc, aC[mt]);
            aG[mt] = MFMA16(a, bg, aG[mt]);
        }
    }
    __syncthreads();

    const float bC1 = cb1[col], bG1 = gb1[col];
    #pragma unroll
    for (int mt = 0; mt < 4; ++mt){
        #pragma unroll
        for (int j = 0; j < 4; ++j){
            int row = mt * 16 + grp * 4 + j;
            ldsHC[row * 74 + col] = f2bf(silu_(aC[mt][j] + bC1));
            ldsHG[row * 74 + col] = f2bf(silu_(aG[mt][j] + bG1));
        }
    }
    __syncthreads();

    f32x4 oC[4] = {}, oG[4] = {};
    #pragma unroll
    for (int kt = 0; kt < 2; ++kt){
        s16x8 bc = *(const s16x8*)&w2cT[col * 64 + kt * 32 + grp * 8];
        s16x8 bg = *(const s16x8*)&w2gT[col * 64 + kt * 32 + grp * 8];
        #pragma unroll
        for (int mt = 0; mt < 4; ++mt){
            s16x8 hc = *(const s16x8*)&ldsHC[(mt * 16 + r16) * 74 + kt * 32 + grp * 8];
            s16x8 hg = *(const s16x8*)&ldsHG[(mt * 16 + r16) * 74 + kt * 32 + grp * 8];
            oC[mt] = MFMA16(hc, bc, oC[mt]);
            oG[mt] = MFMA16(hg, bg, oG[mt]);
        }
    }
    const float bC2 = cb2[col], bG2 = gb2[col];
    #pragma unroll
    for (int mt = 0; mt < 4; ++mt){
        #pragma unroll
        for (int j = 0; j < 4; ++j){
            int row = mt * 16 + grp * 4 + j;
            float v = silu_(oC[mt][j] + bC2) * sigm_(oG[mt][j] + bG2);
            v *= bf2f(bwv[mt * 4 + j]);
            ldsV[row * 74 + col] = f2bf(v);
        }
    }
    __syncthreads();

    f32x4 oD[4] = {};
    #pragma unroll
    for (int kt = 0; kt < 2; ++kt){
        s16x8 bo = *(const s16x8*)&woT[col * 64 + kt * 32 + grp * 8];
        #pragma unroll
        for (int mt = 0; mt < 4; ++mt){
            s16x8 a = *(const s16x8*)&ldsV[(mt * 16 + r16) * 74 + kt * 32 + grp * 8];
            oD[mt] = MFMA16(a, bo, oD[mt]);
        }
    }
    #pragma unroll
    for (int mt = 0; mt < 4; ++mt){
        #pragma unroll
        for (int j = 0; j < 4; ++j){
            int row = mt * 16 + grp * 4 + j;
            upd[(size_t)(r0 + row) * 64 + col] = f2bf(oD[mt][j]);   // dense in sorted space
        }
    }
}

// ---------------- angle update (sorted by bgi), in-place residual on angleBf
__global__ __launch_bounds__(256, 4) void k_angle(
    const unsigned short* __restrict__ atomBf, const unsigned short* __restrict__ bondBf,
    unsigned short* __restrict__ angleBf,
    const int* __restrict__ bga, const int* __restrict__ bgb,
    const int* __restrict__ idxB,
    const unsigned short* __restrict__ wcT, const unsigned short* __restrict__ wgT,
    const float* __restrict__ cb, const float* __restrict__ gb)
{
    __shared__ unsigned short ldsA[64 * 264];
    __shared__ int ldsSrc[256];
    const int tid = threadIdx.x;
    const int r0  = blockIdx.x * 64;

    {
        int q = tid >> 6, row = tid & 63;
        int a = idxB[r0 + row];
        int s;
        if (q == 0)      s = bgb[2 * a];
        else if (q == 1) s = bgb[2 * a + 1];
        else if (q == 2) s = a;
        else             s = bga[a];
        ldsSrc[tid] = s;
    }
    __syncthreads();
    {
        const int lane8 = tid & 7;
        #pragma unroll
        for (int p = 0; p < 8; ++p){
            int cc = p * 32 + (tid >> 3);
            int q = cc >> 6, row = cc & 63;
            int s = ldsSrc[cc];
            const unsigned short* buf = (q < 2) ? bondBf : (q == 2 ? angleBf : atomBf);
            u32x4 v = *(const u32x4*)(buf + (size_t)s * 64 + lane8 * 8);
            *(u32x4*)&ldsA[row * 264 + q * 64 + lane8 * 8] = v;
        }
    }
    __syncthreads();

    const int lane = tid & 63;
    const int r16  = lane & 15;
    const int grp  = lane >> 4;
    const int col  = (tid >> 6) * 16 + r16;

    f32x4 aC[4] = {}, aG[4] = {};
    #pragma unroll
    for (int kt = 0; kt < 8; ++kt){
        s16x8 bc = *(const s16x8*)&wcT[col * 256 + kt * 32 + grp * 8];
        s16x8 bg = *(const s16x8*)&wgT[col * 256 + kt * 32 + grp * 8];
        #pragma unroll
        for (int mt = 0; mt < 4; ++mt){
            s16x8 a = *(const s16x8*)&ldsA[(mt * 16 + r16) * 264 + kt * 32 + grp * 8];
            aC[mt] = MFMA16(a, bc, aC[mt]);
            aG[mt] = MFMA16(a, bg, aG[mt]);
        }
    }
    const float bC = cb[col], bG = gb[col];
    #pragma unroll
    for (int mt = 0; mt < 4; ++mt){
        #pragma unroll
        for (int j = 0; j < 4; ++j){
            int row = mt * 16 + grp * 4 + j;
            int a = ldsSrc[128 + row];          // sorted angle id (q==2 slot)
            float oldv = bf2f(ldsA[row * 264 + 128 + col]);
            float v = silu_(aC[mt][j] + bC) * sigm_(aG[mt][j] + bG);
            angleBf[(size_t)a * 64 + col] = f2bf(oldv + v);
        }
    }
}

// ---------------- readout MLP + segmented sum (wave per atom row)
__global__ __launch_bounds__(256) void k_readout(
    const unsigned short* __restrict__ atomBf, const int* __restrict__ owners,
    const float* __restrict__ w1, const float* __restrict__ b1,
    const float* __restrict__ w2, const float* __restrict__ b2,
    const float* __restrict__ w3, const float* __restrict__ b3,
    float* __restrict__ esum, float* __restrict__ cnt)
{
    int gid  = blockIdx.x * 256 + threadIdx.x;
    int n    = gid >> 6;
    int lane = threadIdx.x & 63;
    float a = bf2f(atomBf[n * 64 + lane]);
    float acc = b1[lane];
    #pragma unroll
    for (int k = 0; k < 64; ++k) acc += __shfl(a, k) * w1[k * 64 + lane];
    float h = silu_(acc);
    acc = b2[lane];
    #pragma unroll
    for (int k = 0; k < 64; ++k) acc += __shfl(h, k) * w2[k * 64 + lane];
    h = silu_(acc);
    float p = h * w3[lane];
    #pragma unroll
    for (int off = 32; off > 0; off >>= 1) p += __shfl_xor(p, off);
    if (lane == 0){
        atomicAdd(&esum[owners[n]], p + b3[0]);
        atomicAdd(&cnt[owners[n]], 1.0f);
    }
}

__global__ void k_final(const float* __restrict__ esum, const float* __restrict__ cnt,
                        float* __restrict__ out){
    int i = threadIdx.x;
    if (i < 128) out[i] = esum[i] / fmaxf(cnt[i], 1.0f);
}

extern "C" void kernel_launch(void* const* d_in, const int* in_sizes, int n_in,
                              void* d_out, int out_size, void* d_ws, size_t ws_size,
                              hipStream_t stream)
{
    (void)in_sizes; (void)n_in; (void)out_size; (void)ws_size;
    const int N_ATOMS = 8192, N_UND = 65536, N_DIR = 131072, N_ANG = 262144;

    const int*   atomic_numbers = (const int*)  d_in[0];
    const float* bb_ag  = (const float*)d_in[1];
    const float* bb_bg  = (const float*)d_in[2];
    const float* ang_b  = (const float*)d_in[3];
    const int*   agraph = (const int*)  d_in[4];
    const int*   d2u    = (const int*)  d_in[5];
    const int*   bga    = (const int*)  d_in[6];
    const int*   bgb    = (const int*)  d_in[7];
    const int*   owners = (const int*)  d_in[8];
    const float* emb    = (const float*)d_in[9];
    const float* Wb     = (const float*)d_in[10];
    const float* Wa     = (const float*)d_in[11];
    const float* Wbwag  = (const float*)d_in[12];
    const float* Wbwbg  = (const float*)d_in[13];
    const float* ac_cw1 = (const float*)d_in[14];
    const float* ac_cb1 = (const float*)d_in[15];
    const float* ac_cw2 = (const float*)d_in[16];
    const float* ac_cb2 = (const float*)d_in[17];
    const float* ac_gw1 = (const float*)d_in[18];
    const float* ac_gb1 = (const float*)d_in[19];
    const float* ac_gw2 = (const float*)d_in[20];
    const float* ac_gb2 = (const float*)d_in[21];
    const float* ac_out = (const float*)d_in[22];
    const float* bc_cw1 = (const float*)d_in[23];
    const float* bc_cb1 = (const float*)d_in[24];
    const float* bc_cw2 = (const float*)d_in[25];
    const float* bc_cb2 = (const float*)d_in[26];
    const float* bc_gw1 = (const float*)d_in[27];
    const float* bc_gb1 = (const float*)d_in[28];
    const float* bc_gw2 = (const float*)d_in[29];
    const float* bc_gb2 = (const float*)d_in[30];
    const float* bc_out = (const float*)d_in[31];
    const float* an_cw  = (const float*)d_in[32];
    const float* an_cb  = (const float*)d_in[33];
    const float* an_gw  = (const float*)d_in[34];
    const float* an_gb  = (const float*)d_in[35];
    const float* ro_w1  = (const float*)d_in[36];
    const float* ro_b1  = (const float*)d_in[37];
    const float* ro_w2  = (const float*)d_in[38];
    const float* ro_b2  = (const float*)d_in[39];
    const float* ro_w3  = (const float*)d_in[40];
    const float* ro_b3  = (const float*)d_in[41];

    char* ws = (char*)d_ws;
    size_t off = 0;
    auto alloc = [&](size_t bytes) -> void* {
        void* p = ws + off;
        off = (off + bytes + 255) & ~(size_t)255;
        return p;
    };
    unsigned short* atomBf  = (unsigned short*)alloc((size_t)N_ATOMS * 64 * 2);
    unsigned short* bondBf  = (unsigned short*)alloc((size_t)N_UND   * 64 * 2);
    unsigned short* angleBf = (unsigned short*)alloc((size_t)N_ANG   * 64 * 2);
    unsigned short* bwagBf  = (unsigned short*)alloc((size_t)N_UND   * 64 * 2);
    unsigned short* bwbgBf  = (unsigned short*)alloc((size_t)N_UND   * 64 * 2);
    unsigned short* updBuf  = (unsigned short*)alloc((size_t)N_ANG   * 64 * 2);
    float* esum   = (float*)alloc(128 * 4);
    float* cnt    = (float*)alloc(128 * 4);
    int* offsA = (int*)alloc((N_ATOMS + 1) * 4);
    int* curA  = (int*)alloc(N_ATOMS * 4);
    int* idxA  = (int*)alloc((size_t)N_DIR * 4);
    int* offsB = (int*)alloc((N_UND + 1) * 4);
    int* curB  = (int*)alloc(N_UND * 4);
    int* idxB  = (int*)alloc((size_t)N_ANG * 4);
    int* bsum  = (int*)alloc(256 * 4);
    int* bbase = (int*)alloc(256 * 4);
    unsigned short* acw1cT = (unsigned short*)alloc((size_t)4 * 64 * 192 * 2);
    unsigned short* acw1gT = (unsigned short*)alloc((size_t)4 * 64 * 192 * 2);
    unsigned short* acw2cT = (unsigned short*)alloc((size_t)4 * 64 * 64 * 2);
    unsigned short* acw2gT = (unsigned short*)alloc((size_t)4 * 64 * 64 * 2);
    unsigned short* acoT   = (unsigned short*)alloc((size_t)4 * 64 * 64 * 2);
    unsigned short* bcw1cT = (unsigned short*)alloc((size_t)3 * 64 * 256 * 2);
    unsigned short* bcw1gT = (unsigned short*)alloc((size_t)3 * 64 * 256 * 2);
    unsigned short* bcw2cT = (unsigned short*)alloc((size_t)3 * 64 * 64 * 2);
    unsigned short* bcw2gT = (unsigned short*)alloc((size_t)3 * 64 * 64 * 2);
    unsigned short* bcoT   = (unsigned short*)alloc((size_t)3 * 64 * 64 * 2);
    unsigned short* anwcT  = (unsigned short*)alloc((size_t)3 * 64 * 256 * 2);
    unsigned short* anwgT  = (unsigned short*)alloc((size_t)3 * 64 * 256 * 2);

    auto tc = [&](const float* src, unsigned short* dst, int B, int K){
        int total = B * K * 64;
        k_transconv<<<(total + 255) / 256, 256, 0, stream>>>(src, dst, K, total);
    };
    tc(ac_cw1, acw1cT, 4, 192);  tc(ac_gw1, acw1gT, 4, 192);
    tc(ac_cw2, acw2cT, 4, 64);   tc(ac_gw2, acw2gT, 4, 64);
    tc(ac_out, acoT,   4, 64);
    tc(bc_cw1, bcw1cT, 3, 256);  tc(bc_gw1, bcw1gT, 3, 256);
    tc(bc_cw2, bcw2cT, 3, 64);   tc(bc_gw2, bcw2gT, 3, 64);
    tc(bc_out, bcoT,   3, 64);
    tc(an_cw,  anwcT,  3, 256);  tc(an_gw,  anwgT,  3, 256);

    k_embed<<<N_ATOMS * 64 / 256, 256, 0, stream>>>(emb, atomic_numbers, atomBf);
    k_smallmm<<<N_UND * 64 / 256, 256, 0, stream>>>(bb_ag, Wb,    bondBf);
    k_smallmm<<<N_ANG * 64 / 256, 256, 0, stream>>>(ang_b, Wa,    angleBf);
    k_smallmm<<<N_UND * 64 / 256, 256, 0, stream>>>(bb_ag, Wbwag, bwagBf);
    k_smallmm<<<N_UND * 64 / 256, 256, 0, stream>>>(bb_bg, Wbwbg, bwbgBf);

    // CSR build (graph static across iterations), hierarchical scan
    hipMemsetAsync(curA, 0, N_ATOMS * 4, stream);
    k_count<<<(N_DIR + 255) / 256, 256, 0, stream>>>(agraph, 2, N_DIR, curA);
    k_bsum <<<N_ATOMS / 256, 256, 0, stream>>>(curA, bsum);
    k_bscan<<<1, 256, 0, stream>>>(bsum, bbase, N_ATOMS / 256, offsA + N_ATOMS);
    k_offs <<<N_ATOMS / 256, 256, 0, stream>>>(curA, bbase, offsA);
    hipMemsetAsync(curA, 0, N_ATOMS * 4, stream);
    k_fill<<<(N_DIR + 255) / 256, 256, 0, stream>>>(agraph, 2, N_DIR, offsA, curA, idxA);

    hipMemsetAsync(curB, 0, N_UND * 4, stream);
    k_count<<<(N_ANG + 255) / 256, 256, 0, stream>>>(bgb, 2, N_ANG, curB);
    k_bsum <<<N_UND / 256, 256, 0, stream>>>(curB, bsum);
    k_bscan<<<1, 256, 0, stream>>>(bsum, bbase, N_UND / 256, offsB + N_UND);
    k_offs <<<N_UND / 256, 256, 0, stream>>>(curB, bbase, offsB);
    hipMemsetAsync(curB, 0, N_UND * 4, stream);
    k_fill<<<(N_ANG + 255) / 256, 256, 0, stream>>>(bgb, 2, N_ANG, offsB, curB, idxB);

    for (int i = 0; i < 4; ++i){
        k_atom_conv<<<N_DIR / 64, 256, 0, stream>>>(
            atomBf, bondBf, bwagBf, agraph, d2u, idxA,
            acw1cT + (size_t)i * 64 * 192, acw1gT + (size_t)i * 64 * 192,
            acw2cT + (size_t)i * 64 * 64,  acw2gT + (size_t)i * 64 * 64,
            acoT   + (size_t)i * 64 * 64,
            ac_cb1 + i * 64, ac_cb2 + i * 64, ac_gb1 + i * 64, ac_gb2 + i * 64, updBuf);
        k_reduce<<<N_ATOMS * 8 / 256, 256, 0, stream>>>(updBuf, offsA, atomBf, N_ATOMS);
        if (i == 3) break;
        k_bond_conv<<<N_ANG / 64, 256, 0, stream>>>(
            atomBf, bondBf, angleBf, bwbgBf, bga, bgb, idxB,
            bcw1cT + (size_t)i * 64 * 256, bcw1gT + (size_t)i * 64 * 256,
            bcw2cT + (size_t)i * 64 * 64,  bcw2gT + (size_t)i * 64 * 64,
            bcoT   + (size_t)i * 64 * 64,
            bc_cb1 + i * 64, bc_cb2 + i * 64, bc_gb1 + i * 64, bc_gb2 + i * 64, updBuf);
        k_reduce<<<N_UND * 8 / 256, 256, 0, stream>>>(updBuf, offsB, bondBf, N_UND);
        k_angle<<<N_ANG / 64, 256, 0, stream>>>(
            atomBf, bondBf, angleBf, bga, bgb, idxB,
            anwcT + (size_t)i * 64 * 256, anwgT + (size_t)i * 64 * 256,
            an_cb + i * 64, an_gb + i * 64);
    }

    hipMemsetAsync(esum, 0, 128 * 4, stream);
    hipMemsetAsync(cnt,  0, 128 * 4, stream);
    k_readout<<<N_ATOMS * 64 / 256, 256, 0, stream>>>(
        atomBf, owners, ro_w1, ro_b1, ro_w2, ro_b2, ro_w3, ro_b3, esum, cnt);
    k_final<<<1, 128, 0, stream>>>(esum, cnt, (float*)d_out);
}